// Round 7
// baseline (368.204 us; speedup 1.0000x reference)
//
#include <hip/hip_runtime.h>

typedef unsigned short ushort_t;
typedef unsigned int uint32;

#define NTOK 4096
#define SEQ 2048
#define DDIM 768
#define HDIM 3072
#define NEXP 8
#define KKEEP 819
#define MTILE 128
#define MAXTILES 40
#define MAXSLOTS 5120

typedef __attribute__((ext_vector_type(8))) short bfrag8;   // 8 bf16 (4 VGPRs)
typedef __attribute__((ext_vector_type(4))) float facc4;    // 4 fp32 acc

__device__ __forceinline__ ushort_t f2bf(float f) {
  uint32 x = __float_as_uint(f);
  uint32 r = (x + 0x7FFFu + ((x >> 16) & 1u)) >> 16;
  return (ushort_t)r;
}
// gelu = 0.5u(1+tanh(z)) = u / (1 + e^{-2z}), z = 0.79788456(u+0.044715u^3)
// exp2-based: branchless v_exp_f32 + v_rcp_f32 (~8 VALU ops vs ocml tanhf ~60)
__device__ __forceinline__ float gelu_f(float u) {
  float z = u + 0.044715f * u * u * u;
  float e = __builtin_amdgcn_exp2f(-2.3021840216f * z);  // 2*0.79788456*log2(e)
  return u * __builtin_amdgcn_rcpf(1.f + e);
}

// async global->LDS, 16 bytes per lane, LDS dest contiguous in lane order
#define GL2LDS(gp, lp)                                                        \
  __builtin_amdgcn_global_load_lds(                                           \
      (const __attribute__((address_space(1))) void*)(gp),                    \
      (__attribute__((address_space(3))) void*)(lp), 16, 0, 0)

// ---------------- gate: softmax top-1 expert + mask score + v init --------------
__global__ __launch_bounds__(256) void k_gate(
    const float* __restrict__ x, const float* __restrict__ Wg,
    const float* __restrict__ bg, const float* __restrict__ Wm,
    const float* __restrict__ bm, const float* __restrict__ bv,
    int* __restrict__ expert, float* __restrict__ topp,
    float* __restrict__ score, float* __restrict__ v) {
  int tid = threadIdx.x, lane = tid & 63, w = tid >> 6;
  int t = blockIdx.x * 4 + w;
  float g[8];
#pragma unroll
  for (int e = 0; e < 8; ++e) g[e] = 0.f;
  float sm = 0.f;
  for (int d = lane; d < DDIM; d += 64) {
    float xv = x[(size_t)t * DDIM + d];
    float4 w0 = *(const float4*)(Wg + d * 8);
    float4 w1 = *(const float4*)(Wg + d * 8 + 4);
    g[0] += xv * w0.x; g[1] += xv * w0.y; g[2] += xv * w0.z; g[3] += xv * w0.w;
    g[4] += xv * w1.x; g[5] += xv * w1.y; g[6] += xv * w1.z; g[7] += xv * w1.w;
    sm += xv * Wm[d];
  }
#pragma unroll
  for (int e = 0; e < 8; ++e) {
#pragma unroll
    for (int off = 32; off > 0; off >>= 1) g[e] += __shfl_down(g[e], off, 64);
  }
#pragma unroll
  for (int off = 32; off > 0; off >>= 1) sm += __shfl_down(sm, off, 64);
  if (lane == 0) {
    float l[8];
#pragma unroll
    for (int e = 0; e < 8; ++e) l[e] = g[e] + bg[e];
    int am = 0;
    float mx = l[0];
#pragma unroll
    for (int e = 1; e < 8; ++e) {
      if (l[e] > mx) { mx = l[e]; am = e; }  // first-max = jnp.argmax
    }
    float s = 0.f;
#pragma unroll
    for (int e = 0; e < 8; ++e) s += expf(l[e] - mx);
    expert[t] = am;
    topp[t] = 1.f / s;
    float z = sm + bm[0];
    score[t] = 1.f / (1.f + expf(-z));
    v[t] = bv[0];  // init for gemm2's fused vdot atomic accumulation
  }
}

// ---------------- merged: histogram top-K threshold (b<2) + bucket (b==2) -------
__global__ __launch_bounds__(256) void k_thrbucket(
    const float* __restrict__ score, float* __restrict__ thr,
    const int* __restrict__ expert, int* __restrict__ meta,
    int* __restrict__ tiles, int* __restrict__ slot_token) {
  int tid = threadIdx.x;
  if (blockIdx.x < 2) {
    int b = blockIdx.x;
    __shared__ uint32 chist[256];
    __shared__ float vals[2048];
    __shared__ uint32 scnt;
    __shared__ int bstar_s, kprime_s;
    chist[tid] = 0;
    if (tid == 0) scnt = 0;
    __syncthreads();
    for (int i = tid; i < SEQ; i += 256) {
      float s = score[b * SEQ + i];
      int bin = min(255, max(0, (int)(s * 256.f)));
      atomicAdd(&chist[bin], 1u);
    }
    __syncthreads();
    if (tid == 0) {
      int cum = 0;
      for (int j = 255; j >= 0; --j) {
        cum += (int)chist[j];
        if (cum >= KKEEP) {
          bstar_s = j;
          kprime_s = KKEEP - (cum - (int)chist[j]);
          break;
        }
      }
    }
    __syncthreads();
    int bstar = bstar_s, kprime = kprime_s;
    for (int i = tid; i < SEQ; i += 256) {
      float s = score[b * SEQ + i];
      int bin = min(255, max(0, (int)(s * 256.f)));
      if (bin == bstar) vals[atomicAdd(&scnt, 1u)] = s;
    }
    __syncthreads();
    int n = (int)scnt;
    for (int ci = tid; ci < n; ci += 256) {
      float xx = vals[ci];
      int g = 0, eq = 0;
      for (int j = 0; j < n; ++j) {
        g += (vals[j] > xx);
        eq += (vals[j] == xx);
      }
      if (g < kprime && kprime <= g + eq) thr[b] = xx;  // exact K-th largest
    }
  } else {
    __shared__ int cnt[NEXP];
    __shared__ int off[NEXP];
    if (tid < NEXP) cnt[tid] = 0;
    __syncthreads();
    for (int t = tid; t < NTOK; t += 256) atomicAdd(&cnt[expert[t]], 1);
    __syncthreads();
    if (tid == 0) {
      int run = 0, nt = 0;
      for (int e = 0; e < NEXP; ++e) {
        off[e] = run;
        int c = cnt[e];
        int padded = (c + MTILE - 1) / MTILE * MTILE;
        for (int s = 0; s < padded; s += MTILE)
          tiles[nt++] = (e << 16) | (run + s);
        run += padded;
      }
      meta[0] = nt;
      meta[1] = run;
    }
    __syncthreads();
    for (int s = tid; s < MAXSLOTS; s += 256) slot_token[s] = -1;
    __syncthreads();
    for (int t = tid; t < NTOK; t += 256) {
      int p = atomicAdd(&off[expert[t]], 1);
      slot_token[p] = t;
    }
  }
}

// ---------------- merged: x-gather (bx<MAXSLOTS) + W1 transpose -----------------
// wt part: fp32 [e][K][N] -> bf16 [e][N][K], 64x64 tiles, flat grid
__global__ __launch_bounds__(256) void k_prep(
    const float* __restrict__ x, const int* __restrict__ slot_token,
    ushort_t* __restrict__ xp, const float* __restrict__ src,
    ushort_t* __restrict__ dst, int K, int N, int nkb) {
  __shared__ float t[64][65];
  int bx = blockIdx.x;
  int tid = threadIdx.x;
  if (bx < MAXSLOTS) {
    int tok = slot_token[bx];
    for (int d = tid; d < DDIM; d += 256) {
      float vv = (tok >= 0) ? x[(size_t)tok * DDIM + d] : 0.f;
      xp[(size_t)bx * DDIM + d] = f2bf(vv);
    }
    return;
  }
  int bi = bx - MAXSLOTS;
  int per_e = nkb * (N / 64);
  int e = bi / per_e, rem = bi % per_e;
  int k0 = (rem % nkb) * 64, n0 = (rem / nkb) * 64;
  const float* S = src + (size_t)e * K * N;
  ushort_t* D = dst + (size_t)e * N * K;
  int r = tid >> 4, c4 = (tid & 15) * 4;
#pragma unroll
  for (int it = 0; it < 4; ++it) {
    int k = r + it * 16;
    float4 vv = *(const float4*)(S + (size_t)(k0 + k) * N + n0 + c4);
    t[k][c4] = vv.x; t[k][c4 + 1] = vv.y; t[k][c4 + 2] = vv.z; t[k][c4 + 3] = vv.w;
  }
  __syncthreads();
#pragma unroll
  for (int it = 0; it < 4; ++it) {
    int n = r + it * 16;
    ushort4 o;
    o.x = f2bf(t[c4][n]); o.y = f2bf(t[c4 + 1][n]);
    o.z = f2bf(t[c4 + 2][n]); o.w = f2bf(t[c4 + 3][n]);
    *(ushort4*)(D + (size_t)(n0 + n) * K + k0 + c4) = o;
  }
}

// standalone weight transpose (W2), flat grid
__global__ __launch_bounds__(256) void k_wt(const float* __restrict__ src,
                                            ushort_t* __restrict__ dst, int K,
                                            int N, int nkb) {
  __shared__ float t[64][65];
  int bi = blockIdx.x;
  int per_e = nkb * (N / 64);
  int e = bi / per_e, rem = bi % per_e;
  int k0 = (rem % nkb) * 64, n0 = (rem / nkb) * 64;
  const float* S = src + (size_t)e * K * N;
  ushort_t* D = dst + (size_t)e * N * K;
  int tid = threadIdx.x;
  int r = tid >> 4, c4 = (tid & 15) * 4;
#pragma unroll
  for (int it = 0; it < 4; ++it) {
    int k = r + it * 16;
    float4 vv = *(const float4*)(S + (size_t)(k0 + k) * N + n0 + c4);
    t[k][c4] = vv.x; t[k][c4 + 1] = vv.y; t[k][c4 + 2] = vv.z; t[k][c4 + 3] = vv.w;
  }
  __syncthreads();
#pragma unroll
  for (int it = 0; it < 4; ++it) {
    int n = r + it * 16;
    ushort4 o;
    o.x = f2bf(t[c4][n]); o.y = f2bf(t[c4 + 1][n]);
    o.z = f2bf(t[c4 + 2][n]); o.w = f2bf(t[c4 + 3][n]);
    *(ushort4*)(D + (size_t)(n0 + n) * K + k0 + c4) = o;
  }
}

// ---------------- grouped MFMA GEMM layer 1: h = gelu(xp @ W1 + b1) -------------
// M-split x2: 64x128 output tile, grid 40x24x2 = 1920 blocks (~7.5/CU) so
// wave-level TLP hides the barrier drain (round-5 lever). Coalesced staging
// (8 lines/GL2LDS) + chunk-XOR swizzle (both-sides involution), BK=64.
__global__ __launch_bounds__(256) void k_gemm1(
    const ushort_t* __restrict__ xp, const ushort_t* __restrict__ Wt,
    const float* __restrict__ b1, const int* __restrict__ meta,
    const int* __restrict__ tiles, ushort_t* __restrict__ h) {
  __shared__ ushort_t As[64 * 64];   // 8 KB
  __shared__ ushort_t Bs[128 * 64];  // 16 KB
  if ((int)blockIdx.x >= meta[0]) return;
  int desc = tiles[blockIdx.x];
  int e = desc >> 16;
  int slot0 = (desc & 0xFFFF) + ((int)blockIdx.z << 6);  // 64-row half
  int n0 = blockIdx.y * 128;
  int tid = threadIdx.x;
  int lane = tid & 63, w = tid >> 6;
  int mq = (w & 1) << 5;   // 0 / 32
  int nq = (w >> 1) << 6;  // 0 / 64
  int mrow = lane & 15, quad = lane >> 4;
  int rl = tid >> 3;                  // row 0..31 (+32 per round)
  int sw = (tid & 7) ^ (rl & 7);      // pre-swizzled global chunk
  const ushort_t* Ag = xp + (size_t)(slot0 + rl) * 768 + sw * 8;
  const ushort_t* Bg = Wt + ((size_t)e * 3072 + n0 + rl) * 768 + sw * 8;
  facc4 acc[2][4];
  facc4 zero = {0.f, 0.f, 0.f, 0.f};
#pragma unroll
  for (int i = 0; i < 2; ++i)
#pragma unroll
    for (int j = 0; j < 4; ++j) acc[i][j] = zero;
  for (int k0 = 0; k0 < 768; k0 += 64) {
#pragma unroll
    for (int r = 0; r < 2; ++r)
      GL2LDS(Ag + k0 + (size_t)r * 32 * 768, As + (r * 256 + tid) * 8);
#pragma unroll
    for (int r = 0; r < 4; ++r)
      GL2LDS(Bg + k0 + (size_t)r * 32 * 768, Bs + (r * 256 + tid) * 8);
    __syncthreads();
#pragma unroll
    for (int kk = 0; kk < 2; ++kk) {
      bfrag8 a[2], b[4];
      int ph = (((kk << 2) + quad) ^ (mrow & 7)) << 3;
#pragma unroll
      for (int i = 0; i < 2; ++i)
        a[i] = *(const bfrag8*)(As + ((mq + i * 16 + mrow) << 6) + ph);
#pragma unroll
      for (int j = 0; j < 4; ++j)
        b[j] = *(const bfrag8*)(Bs + ((nq + j * 16 + mrow) << 6) + ph);
#pragma unroll
      for (int i = 0; i < 2; ++i)
#pragma unroll
        for (int j = 0; j < 4; ++j)
          acc[i][j] = __builtin_amdgcn_mfma_f32_16x16x32_bf16(a[i], b[j],
                                                              acc[i][j], 0, 0, 0);
    }
    __syncthreads();
  }
  const float* bb = b1 + (size_t)e * 3072 + n0;
#pragma unroll
  for (int i = 0; i < 2; ++i) {
    int mo = mq + i * 16 + (quad << 2);
#pragma unroll
    for (int j = 0; j < 4; ++j) {
      int nc = nq + j * 16 + mrow;
      float bias = bb[nc];
#pragma unroll
      for (int r = 0; r < 4; ++r) {
        float val = gelu_f(acc[i][j][r] + bias);
        h[(size_t)(slot0 + mo + r) * 3072 + n0 + nc] = f2bf(val);
      }
    }
  }
}

// ---------------- grouped MFMA GEMM layer 2 + fused vdot ------------------------
// M-split x2 (64x64 tile, 960 blocks) + BK=128: 24 iterations, 16 MFMA/lane per
// barrier -> per-iter drain amortized 2x vs BK=64. LDS [row][128] with 4-bit
// chunk-XOR swizzle (same involution family; 2 lanes/16B slot = free).
__global__ __launch_bounds__(256) void k_gemm2(
    const ushort_t* __restrict__ h, const ushort_t* __restrict__ Wt,
    const float* __restrict__ b2, const float* __restrict__ topp,
    const float* __restrict__ Wv, const int* __restrict__ meta,
    const int* __restrict__ tiles, const int* __restrict__ slot_token,
    float* __restrict__ outf, float* __restrict__ v) {
  __shared__ ushort_t As[64 * 128];  // 16 KB
  __shared__ ushort_t Bs[64 * 128];  // 16 KB
  if ((int)blockIdx.x >= meta[0]) return;
  int desc = tiles[blockIdx.x];
  int e = desc >> 16;
  int slot0 = (desc & 0xFFFF) + ((int)blockIdx.z << 6);  // 64-row half
  int n0 = blockIdx.y * 64;          // 12 n-blocks
  int tid = threadIdx.x;
  int lane = tid & 63, w = tid >> 6;
  int mq = (w & 1) << 5;   // 0 / 32
  int nq = (w >> 1) << 5;  // 0 / 32
  int mrow = lane & 15, quad = lane >> 4;
  int rl = tid >> 4;                  // row 0..15 (+16 per round)
  int sw = (tid & 15) ^ (rl & 7);     // pre-swizzled global chunk (4-bit)
  const ushort_t* Ag = h + (size_t)(slot0 + rl) * 3072 + sw * 8;
  const ushort_t* Bg = Wt + ((size_t)e * 768 + n0 + rl) * 3072 + sw * 8;
  facc4 acc[2][2];
  facc4 zero = {0.f, 0.f, 0.f, 0.f};
#pragma unroll
  for (int i = 0; i < 2; ++i)
#pragma unroll
    for (int j = 0; j < 2; ++j) acc[i][j] = zero;
  for (int k0 = 0; k0 < 3072; k0 += 128) {
#pragma unroll
    for (int r = 0; r < 4; ++r)
      GL2LDS(Ag + k0 + (size_t)r * 16 * 3072, As + (r * 256 + tid) * 8);
#pragma unroll
    for (int r = 0; r < 4; ++r)
      GL2LDS(Bg + k0 + (size_t)r * 16 * 3072, Bs + (r * 256 + tid) * 8);
    __syncthreads();
#pragma unroll
    for (int kk = 0; kk < 4; ++kk) {
      bfrag8 a[2], b[2];
      int ph = (((kk << 2) + quad) ^ (mrow & 7)) << 3;
#pragma unroll
      for (int i = 0; i < 2; ++i)
        a[i] = *(const bfrag8*)(As + ((mq + i * 16 + mrow) << 7) + ph);
#pragma unroll
      for (int j = 0; j < 2; ++j)
        b[j] = *(const bfrag8*)(Bs + ((nq + j * 16 + mrow) << 7) + ph);
#pragma unroll
      for (int i = 0; i < 2; ++i)
#pragma unroll
        for (int j = 0; j < 2; ++j)
          acc[i][j] = __builtin_amdgcn_mfma_f32_16x16x32_bf16(a[i], b[j],
                                                              acc[i][j], 0, 0, 0);
    }
    __syncthreads();
  }
  const float* bb = b2 + (size_t)e * 768 + n0;
  float wv0 = Wv[n0 + nq + mrow];
  float wv1 = Wv[n0 + nq + 16 + mrow];
  float bb0 = bb[nq + mrow], bb1 = bb[nq + 16 + mrow];
#pragma unroll
  for (int i = 0; i < 2; ++i) {
    int mo = mq + i * 16 + (quad << 2);
#pragma unroll
    for (int r = 0; r < 4; ++r) {
      int slot = slot0 + mo + r;
      int tok = slot_token[slot];  // uniform within 16-lane quad segment
      if (tok < 0) continue;
      float tp = topp[tok];
      float f0 = tp * (acc[i][0][r] + bb0);
      float f1 = tp * (acc[i][1][r] + bb1);
      outf[(size_t)tok * 768 + n0 + nq + mrow] = f0;
      outf[(size_t)tok * 768 + n0 + nq + 16 + mrow] = f1;
      float pv = f0 * wv0 + f1 * wv1;
#pragma unroll
      for (int off = 8; off > 0; off >>= 1) pv += __shfl_down(pv, off, 16);
      if (mrow == 0) atomicAdd(&v[tok], pv);
    }
  }
}

// ---------------- BK parallel scan: Mobius matrices, 3-level scan ---------------
struct CM {
  float ar, ai, br, bi, cr, ci, dr, di;  // [[a,b],[c,d]] complex
};
__device__ __forceinline__ CM cmmul(const CM& A, const CM& B) {  // A*B
  CM C;
  C.ar = A.ar * B.ar - A.ai * B.ai + A.br * B.cr - A.bi * B.ci;
  C.ai = A.ar * B.ai + A.ai * B.ar + A.br * B.ci + A.bi * B.cr;
  C.br = A.ar * B.br - A.ai * B.bi + A.br * B.dr - A.bi * B.di;
  C.bi = A.ar * B.bi + A.ai * B.br + A.br * B.di + A.bi * B.dr;
  C.cr = A.cr * B.ar - A.ci * B.ai + A.dr * B.cr - A.di * B.ci;
  C.ci = A.cr * B.ai + A.ci * B.ar + A.dr * B.ci + A.di * B.cr;
  C.dr = A.cr * B.br - A.ci * B.bi + A.dr * B.dr - A.di * B.di;
  C.di = A.cr * B.bi + A.ci * B.br + A.dr * B.di + A.di * B.dr;
  return C;
}
__device__ __forceinline__ void cmnorm(CM& A) {
  float m = fmaxf(fmaxf(fmaxf(fabsf(A.ar), fabsf(A.ai)),
                        fmaxf(fabsf(A.br), fabsf(A.bi))),
                  fmaxf(fmaxf(fabsf(A.cr), fabsf(A.ci)),
                        fmaxf(fabsf(A.dr), fabsf(A.di))));
  float s = 1.0f / fmaxf(m, 1e-30f);
  A.ar *= s; A.ai *= s; A.br *= s; A.bi *= s;
  A.cr *= s; A.ci *= s; A.dr *= s; A.di *= s;
}
__device__ __forceinline__ CM cmshfl_up(const CM& A, int off) {
  CM B;
  B.ar = __shfl_up(A.ar, off, 64); B.ai = __shfl_up(A.ai, off, 64);
  B.br = __shfl_up(A.br, off, 64); B.bi = __shfl_up(A.bi, off, 64);
  B.cr = __shfl_up(A.cr, off, 64); B.ci = __shfl_up(A.ci, off, 64);
  B.dr = __shfl_up(A.dr, off, 64); B.di = __shfl_up(A.di, off, 64);
  return B;
}

__global__ __launch_bounds__(256) void k_bkscan(
    const float* __restrict__ v, float* __restrict__ Ar, float* __restrict__ Ai,
    float* __restrict__ Br, float* __restrict__ Bi) {
  int b = blockIdx.x >> 1, rev = blockIdx.x & 1;
  int tid = threadIdx.x, lane = tid & 63, wv = tid >> 6;
  const float* vb = v + b * SEQ;
  float dv[8];
  int sbase = tid * 8;
#pragma unroll
  for (int q = 0; q < 8; ++q) {
    int s = sbase + q;
    int n = rev ? (SEQ - 1 - s) : s;
    dv[q] = fminf(3.f, fmaxf(-3.f, vb[n]));
  }
  CM L;
  L.ar = dv[0]; L.ai = -1.f; L.br = -1.f; L.bi = 0.f;
  L.cr = 1.f; L.ci = 0.f; L.dr = 0.f; L.di = 0.f;
#pragma unroll
  for (int q = 1; q < 8; ++q) {
    float dr = dv[q];
    float nar = dr * L.ar + L.ai - L.cr;
    float nai = dr * L.ai - L.ar - L.ci;
    float nbr = dr * L.br + L.bi - L.dr;
    float nbi = dr * L.bi - L.br - L.di;
    L.cr = L.ar; L.ci = L.ai; L.dr = L.br; L.di = L.bi;
    L.ar = nar; L.ai = nai; L.br = nbr; L.bi = nbi;
  }
  cmnorm(L);
  CM I = L;
#pragma unroll
  for (int off = 1; off < 64; off <<= 1) {
    CM P = cmshfl_up(I, off);
    if (lane >= off) {
      I = cmmul(I, P);
      cmnorm(I);
    }
  }
  __shared__ float wag[4][8];
  if (lane == 63) {
    wag[wv][0] = I.ar; wag[wv][1] = I.ai; wag[wv][2] = I.br; wag[wv][3] = I.bi;
    wag[wv][4] = I.cr; wag[wv][5] = I.ci; wag[wv][6] = I.dr; wag[wv][7] = I.di;
  }
  __syncthreads();
  CM E = cmshfl_up(I, 1);
  if (lane == 0) {
    E.ar = 1.f; E.ai = 0.f; E.br = 0.f; E.bi = 0.f;
    E.cr = 0.f; E.ci = 0.f; E.dr = 1.f; E.di = 0.f;
  }
  for (int j = wv - 1; j >= 0; --j) {
    CM Aj;
    Aj.ar = wag[j][0]; Aj.ai = wag[j][1]; Aj.br = wag[j][2]; Aj.bi = wag[j][3];
    Aj.cr = wag[j][4]; Aj.ci = wag[j][5]; Aj.dr = wag[j][6]; Aj.di = wag[j][7];
    E = cmmul(E, Aj);
    cmnorm(E);
  }
  float u0r = E.ar, u0i = E.ai, u1r = E.cr, u1i = E.ci;
  float* Rr = rev ? Br : Ar;
  float* Ri = rev ? Bi : Ai;
#pragma unroll
  for (int q = 0; q < 8; ++q) {
    float dr = dv[q];
    float n0r = dr * u0r + u0i - u1r;
    float n0i = dr * u0i - u0r - u1i;
    u1r = u0r; u1i = u0i; u0r = n0r; u0i = n0i;
    float m = fmaxf(fmaxf(fabsf(u0r), fabsf(u0i)), fmaxf(fabsf(u1r), fabsf(u1i)));
    float sc = 1.f / fmaxf(m, 1e-30f);
    u0r *= sc; u0i *= sc; u1r *= sc; u1i *= sc;
    float den = u1r * u1r + u1i * u1i;
    float arr = (u0r * u1r + u0i * u1i) / den;
    float aii = (u0i * u1r - u0r * u1i) / den;
    int s = sbase + q;
    int n = rev ? (SEQ - 1 - s) : s;
    Rr[b * SEQ + n] = arr;
    Ri[b * SEQ + n] = aii;
  }
}

// ---------------- final (in place on d_out): out += bk_scale*(feats@Wo+bo) ------
__global__ __launch_bounds__(256) void k_final(
    float* __restrict__ outf, const float* __restrict__ v,
    const float* __restrict__ Ar, const float* __restrict__ Ai,
    const float* __restrict__ Br, const float* __restrict__ Bi,
    const float* __restrict__ score, const float* __restrict__ thr,
    const float* __restrict__ Wo, const float* __restrict__ bo,
    const float* __restrict__ bk) {
  int t = blockIdx.x;
  int b = t >> 11;
  float vc = fminf(3.f, fmaxf(-3.f, v[t]));
  float cr = Ar[t] + Br[t] - vc;
  float ci = Ai[t] + Bi[t] + 1.f;
  float den = cr * cr + ci * ci;
  float gr = cr / den, gi = -ci / den;
  bool m = (score[t] >= thr[b]);
  float fr = m ? fminf(10.f, fmaxf(-10.f, gr)) : 0.f;
  float fi = m ? fminf(10.f, fmaxf(-10.f, gi)) : 0.f;
  float bs = bk[0];
  for (int d = threadIdx.x; d < DDIM; d += 256) {
    float o = outf[(size_t)t * DDIM + d] +
              bs * (fr * Wo[d] + fi * Wo[DDIM + d] + bo[d]);
    outf[(size_t)t * DDIM + d] = o;
  }
}

extern "C" void kernel_launch(void* const* d_in, const int* in_sizes, int n_in,
                              void* d_out, int out_size, void* d_ws, size_t ws_size,
                              hipStream_t stream) {
  const float* x  = (const float*)d_in[0];
  const float* Wg = (const float*)d_in[1];
  const float* bg = (const float*)d_in[2];
  const float* W1 = (const float*)d_in[3];
  const float* b1 = (const float*)d_in[4];
  const float* W2 = (const float*)d_in[5];
  const float* b2 = (const float*)d_in[6];
  const float* Wv = (const float*)d_in[7];
  const float* bv = (const float*)d_in[8];
  const float* Wm = (const float*)d_in[9];
  const float* bm = (const float*)d_in[10];
  const float* Wo = (const float*)d_in[11];
  const float* bo = (const float*)d_in[12];
  const float* bk = (const float*)d_in[13];
  float* outf = (float*)d_out;

  unsigned char* w = (unsigned char*)d_ws;
  int*   expert     = (int*)(w + 0);
  float* topp       = (float*)(w + 16384);
  float* score      = (float*)(w + 32768);
  float* v          = (float*)(w + 49152);
  float* Ar         = (float*)(w + 65536);
  float* Ai         = (float*)(w + 81920);
  float* Br         = (float*)(w + 98304);
  float* Bi         = (float*)(w + 114688);
  float* thr        = (float*)(w + 131072);
  int*   meta       = (int*)(w + 131104);
  int*   tiles      = (int*)(w + 131136);
  int*   slot_token = (int*)(w + 131328);            // 5120 ints
  ushort_t* xp      = (ushort_t*)(w + 152064);       // 5120*768  bf16 = 7.9 MB
  ushort_t* h       = (ushort_t*)(w + 8016384);      // 5120*3072 bf16 = 31.5 MB
  ushort_t* Wt      = (ushort_t*)(w + 39473664);     // 8*3072*768 bf16 = 37.7 MB (reused)
  // total ~77.3 MB

  k_gate<<<1024, 256, 0, stream>>>(x, Wg, bg, Wm, bm, bv, expert, topp, score, v);
  k_thrbucket<<<3, 256, 0, stream>>>(score, thr, expert, meta, tiles, slot_token);

  // xperm (5120 blocks) + W1 transpose (4608 blocks) in one launch
  k_prep<<<MAXSLOTS + 4608, 256, 0, stream>>>(x, slot_token, xp, W1, Wt, 768,
                                              3072, 12);
  k_gemm1<<<dim3(MAXTILES, 24, 2), 256, 0, stream>>>(xp, Wt, b1, meta, tiles, h);

  k_wt<<<4608, 256, 0, stream>>>(W2, Wt, 3072, 768, 48);
  k_gemm2<<<dim3(MAXTILES, 12, 2), 256, 0, stream>>>(h, Wt, b2, topp, Wv, meta,
                                                     tiles, slot_token, outf, v);

  k_bkscan<<<4, 256, 0, stream>>>(v, Ar, Ai, Br, Bi);
  k_final<<<NTOK, 256, 0, stream>>>(outf, v, Ar, Ai, Br, Bi, score, thr, Wo, bo, bk);
}

// Round 8
// 335.065 us; speedup vs baseline: 1.0989x; 1.0989x over previous
//
#include <hip/hip_runtime.h>

typedef unsigned short ushort_t;
typedef unsigned int uint32;

#define NTOK 4096
#define SEQ 2048
#define DDIM 768
#define HDIM 3072
#define NEXP 8
#define KKEEP 819
#define MTILE 128
#define MAXTILES 40
#define MAXSLOTS 5120

typedef __attribute__((ext_vector_type(8))) short bfrag8;   // 8 bf16 (4 VGPRs)
typedef __attribute__((ext_vector_type(4))) float facc4;    // 4 fp32 acc

__device__ __forceinline__ ushort_t f2bf(float f) {
  uint32 x = __float_as_uint(f);
  uint32 r = (x + 0x7FFFu + ((x >> 16) & 1u)) >> 16;
  return (ushort_t)r;
}
// gelu = 0.5u(1+tanh(z)) = u / (1 + e^{-2z}), z = 0.79788456(u+0.044715u^3)
// exp2-based: branchless v_exp_f32 + v_rcp_f32 (~8 VALU ops vs ocml tanhf ~60)
__device__ __forceinline__ float gelu_f(float u) {
  float z = u + 0.044715f * u * u * u;
  float e = __builtin_amdgcn_exp2f(-2.3021840216f * z);  // 2*0.79788456*log2(e)
  return u * __builtin_amdgcn_rcpf(1.f + e);
}

// async global->LDS, 16 bytes per lane, LDS dest contiguous in lane order
#define GL2LDS(gp, lp)                                                        \
  __builtin_amdgcn_global_load_lds(                                           \
      (const __attribute__((address_space(1))) void*)(gp),                    \
      (__attribute__((address_space(3))) void*)(lp), 16, 0, 0)

// ---------------- gate: softmax top-1 expert + mask score + v init --------------
__global__ __launch_bounds__(256) void k_gate(
    const float* __restrict__ x, const float* __restrict__ Wg,
    const float* __restrict__ bg, const float* __restrict__ Wm,
    const float* __restrict__ bm, const float* __restrict__ bv,
    int* __restrict__ expert, float* __restrict__ topp,
    float* __restrict__ score, float* __restrict__ v) {
  int tid = threadIdx.x, lane = tid & 63, w = tid >> 6;
  int t = blockIdx.x * 4 + w;
  float g[8];
#pragma unroll
  for (int e = 0; e < 8; ++e) g[e] = 0.f;
  float sm = 0.f;
  for (int d = lane; d < DDIM; d += 64) {
    float xv = x[(size_t)t * DDIM + d];
    float4 w0 = *(const float4*)(Wg + d * 8);
    float4 w1 = *(const float4*)(Wg + d * 8 + 4);
    g[0] += xv * w0.x; g[1] += xv * w0.y; g[2] += xv * w0.z; g[3] += xv * w0.w;
    g[4] += xv * w1.x; g[5] += xv * w1.y; g[6] += xv * w1.z; g[7] += xv * w1.w;
    sm += xv * Wm[d];
  }
#pragma unroll
  for (int e = 0; e < 8; ++e) {
#pragma unroll
    for (int off = 32; off > 0; off >>= 1) g[e] += __shfl_down(g[e], off, 64);
  }
#pragma unroll
  for (int off = 32; off > 0; off >>= 1) sm += __shfl_down(sm, off, 64);
  if (lane == 0) {
    float l[8];
#pragma unroll
    for (int e = 0; e < 8; ++e) l[e] = g[e] + bg[e];
    int am = 0;
    float mx = l[0];
#pragma unroll
    for (int e = 1; e < 8; ++e) {
      if (l[e] > mx) { mx = l[e]; am = e; }  // first-max = jnp.argmax
    }
    float s = 0.f;
#pragma unroll
    for (int e = 0; e < 8; ++e) s += expf(l[e] - mx);
    expert[t] = am;
    topp[t] = 1.f / s;
    float z = sm + bm[0];
    score[t] = 1.f / (1.f + expf(-z));
    v[t] = bv[0];  // init for gemm2's fused vdot atomic accumulation
  }
}

// ---------------- merged: histogram top-K threshold (b<2) + bucket (b==2) -------
__global__ __launch_bounds__(256) void k_thrbucket(
    const float* __restrict__ score, float* __restrict__ thr,
    const int* __restrict__ expert, int* __restrict__ meta,
    int* __restrict__ tiles, int* __restrict__ slot_token) {
  int tid = threadIdx.x;
  if (blockIdx.x < 2) {
    int b = blockIdx.x;
    __shared__ uint32 chist[256];
    __shared__ float vals[2048];
    __shared__ uint32 scnt;
    __shared__ int bstar_s, kprime_s;
    chist[tid] = 0;
    if (tid == 0) scnt = 0;
    __syncthreads();
    for (int i = tid; i < SEQ; i += 256) {
      float s = score[b * SEQ + i];
      int bin = min(255, max(0, (int)(s * 256.f)));
      atomicAdd(&chist[bin], 1u);
    }
    __syncthreads();
    if (tid == 0) {
      int cum = 0;
      for (int j = 255; j >= 0; --j) {
        cum += (int)chist[j];
        if (cum >= KKEEP) {
          bstar_s = j;
          kprime_s = KKEEP - (cum - (int)chist[j]);
          break;
        }
      }
    }
    __syncthreads();
    int bstar = bstar_s, kprime = kprime_s;
    for (int i = tid; i < SEQ; i += 256) {
      float s = score[b * SEQ + i];
      int bin = min(255, max(0, (int)(s * 256.f)));
      if (bin == bstar) vals[atomicAdd(&scnt, 1u)] = s;
    }
    __syncthreads();
    int n = (int)scnt;
    for (int ci = tid; ci < n; ci += 256) {
      float xx = vals[ci];
      int g = 0, eq = 0;
      for (int j = 0; j < n; ++j) {
        g += (vals[j] > xx);
        eq += (vals[j] == xx);
      }
      if (g < kprime && kprime <= g + eq) thr[b] = xx;  // exact K-th largest
    }
  } else {
    __shared__ int cnt[NEXP];
    __shared__ int off[NEXP];
    if (tid < NEXP) cnt[tid] = 0;
    __syncthreads();
    for (int t = tid; t < NTOK; t += 256) atomicAdd(&cnt[expert[t]], 1);
    __syncthreads();
    if (tid == 0) {
      int run = 0, nt = 0;
      for (int e = 0; e < NEXP; ++e) {
        off[e] = run;
        int c = cnt[e];
        int padded = (c + MTILE - 1) / MTILE * MTILE;
        for (int s = 0; s < padded; s += MTILE)
          tiles[nt++] = (e << 16) | (run + s);
        run += padded;
      }
      meta[0] = nt;
      meta[1] = run;
    }
    __syncthreads();
    for (int s = tid; s < MAXSLOTS; s += 256) slot_token[s] = -1;
    __syncthreads();
    for (int t = tid; t < NTOK; t += 256) {
      int p = atomicAdd(&off[expert[t]], 1);
      slot_token[p] = t;
    }
  }
}

// shared transpose body: fp32 [e][K][N] 64x64 tile -> bf16 [e][N][K]
__device__ __forceinline__ void wtile_transpose(const float* __restrict__ src,
                                                ushort_t* __restrict__ dst,
                                                int K, int N, int nkb, int bi,
                                                int tid, float (*t)[65]) {
  int per_e = nkb * (N / 64);
  int e = bi / per_e, rem = bi % per_e;
  int k0 = (rem % nkb) * 64, n0 = (rem / nkb) * 64;
  const float* S = src + (size_t)e * K * N;
  ushort_t* D = dst + (size_t)e * N * K;
  int r = tid >> 4, c4 = (tid & 15) * 4;
#pragma unroll
  for (int it = 0; it < 4; ++it) {
    int k = r + it * 16;
    float4 vv = *(const float4*)(S + (size_t)(k0 + k) * N + n0 + c4);
    t[k][c4] = vv.x; t[k][c4 + 1] = vv.y; t[k][c4 + 2] = vv.z; t[k][c4 + 3] = vv.w;
  }
  __syncthreads();
#pragma unroll
  for (int it = 0; it < 4; ++it) {
    int n = r + it * 16;
    ushort4 o;
    o.x = f2bf(t[c4][n]); o.y = f2bf(t[c4 + 1][n]);
    o.z = f2bf(t[c4 + 2][n]); o.w = f2bf(t[c4 + 3][n]);
    *(ushort4*)(D + (size_t)(n0 + n) * K + k0 + c4) = o;
  }
}

// ---------------- merged: x-gather + W1 transpose (+ W2 transpose if fused) -----
// W2T blocks (bx >= 9728) only exist when the host launches the fused grid; they
// write a SEPARATE W2t buffer so gemm1's W1t reads are unaffected.
__global__ __launch_bounds__(256) void k_prep(
    const float* __restrict__ x, const int* __restrict__ slot_token,
    ushort_t* __restrict__ xp, const float* __restrict__ W1,
    ushort_t* __restrict__ W1t, const float* __restrict__ W2,
    ushort_t* __restrict__ W2t) {
  __shared__ float t[64][65];
  int bx = blockIdx.x;
  int tid = threadIdx.x;
  if (bx < MAXSLOTS) {
    int tok = slot_token[bx];
    for (int d = tid; d < DDIM; d += 256) {
      float vv = (tok >= 0) ? x[(size_t)tok * DDIM + d] : 0.f;
      xp[(size_t)bx * DDIM + d] = f2bf(vv);
    }
    return;
  }
  if (bx < MAXSLOTS + 4608) {
    wtile_transpose(W1, W1t, 768, 3072, 12, bx - MAXSLOTS, tid, t);
  } else {
    wtile_transpose(W2, W2t, 3072, 768, 48, bx - MAXSLOTS - 4608, tid, t);
  }
}

// standalone weight transpose (W2) — fallback when workspace too small to fuse
__global__ __launch_bounds__(256) void k_wt(const float* __restrict__ src,
                                            ushort_t* __restrict__ dst, int K,
                                            int N, int nkb) {
  __shared__ float t[64][65];
  wtile_transpose(src, dst, K, N, nkb, blockIdx.x, threadIdx.x, t);
}

// ---------------- grouped MFMA GEMM layer 1: h = gelu(xp @ W1 + b1) -------------
// Round-5 proven config: 128x128 tile, BK=64, coalesced staging (8 lines/GL2LDS),
// chunk-XOR swizzle (both-sides involution), 0 bank conflicts. 960 blocks.
__global__ __launch_bounds__(256) void k_gemm1(
    const ushort_t* __restrict__ xp, const ushort_t* __restrict__ Wt,
    const float* __restrict__ b1, const int* __restrict__ meta,
    const int* __restrict__ tiles, ushort_t* __restrict__ h) {
  __shared__ ushort_t As[128 * 64];  // 16 KB
  __shared__ ushort_t Bs[128 * 64];  // 16 KB
  if ((int)blockIdx.x >= meta[0]) return;
  int desc = tiles[blockIdx.x];
  int e = desc >> 16, slot0 = desc & 0xFFFF;
  int n0 = blockIdx.y * 128;
  int tid = threadIdx.x;
  int lane = tid & 63, w = tid >> 6;
  int mq = (w & 1) << 6, nq = (w >> 1) << 6;
  int mrow = lane & 15, quad = lane >> 4;
  int rl = tid >> 3;                  // row 0..31 (+32 per round)
  int sw = (tid & 7) ^ (rl & 7);      // pre-swizzled global chunk
  const ushort_t* Ag = xp + (size_t)(slot0 + rl) * 768 + sw * 8;
  const ushort_t* Bg = Wt + ((size_t)e * 3072 + n0 + rl) * 768 + sw * 8;
  facc4 acc[4][4];
  facc4 zero = {0.f, 0.f, 0.f, 0.f};
#pragma unroll
  for (int i = 0; i < 4; ++i)
#pragma unroll
    for (int j = 0; j < 4; ++j) acc[i][j] = zero;
  for (int k0 = 0; k0 < 768; k0 += 64) {
#pragma unroll
    for (int r = 0; r < 4; ++r) {
      GL2LDS(Ag + k0 + (size_t)r * 32 * 768, As + (r * 256 + tid) * 8);
      GL2LDS(Bg + k0 + (size_t)r * 32 * 768, Bs + (r * 256 + tid) * 8);
    }
    __syncthreads();
#pragma unroll
    for (int kk = 0; kk < 2; ++kk) {
      bfrag8 a[4], b[4];
      int ph = (((kk << 2) + quad) ^ (mrow & 7)) << 3;
#pragma unroll
      for (int i = 0; i < 4; ++i)
        a[i] = *(const bfrag8*)(As + ((mq + i * 16 + mrow) << 6) + ph);
#pragma unroll
      for (int j = 0; j < 4; ++j)
        b[j] = *(const bfrag8*)(Bs + ((nq + j * 16 + mrow) << 6) + ph);
#pragma unroll
      for (int i = 0; i < 4; ++i)
#pragma unroll
        for (int j = 0; j < 4; ++j)
          acc[i][j] = __builtin_amdgcn_mfma_f32_16x16x32_bf16(a[i], b[j],
                                                              acc[i][j], 0, 0, 0);
    }
    __syncthreads();
  }
  const float* bb = b1 + (size_t)e * 3072 + n0;
#pragma unroll
  for (int i = 0; i < 4; ++i) {
    int mo = mq + i * 16 + (quad << 2);
#pragma unroll
    for (int j = 0; j < 4; ++j) {
      int nc = nq + j * 16 + mrow;
      float bias = bb[nc];
#pragma unroll
      for (int r = 0; r < 4; ++r) {
        float val = gelu_f(acc[i][j][r] + bias);
        h[(size_t)(slot0 + mo + r) * 3072 + n0 + nc] = f2bf(val);
      }
    }
  }
}

// ---------------- grouped MFMA GEMM layer 2 + fused vdot ------------------------
// Round-5 proven config: M-split x2 (64x64 tile, 960 blocks ~3.75/CU), BK=64,
// [row][64] LDS + 3-bit chunk-XOR (0 conflicts). BK=128 variant regressed
// (round 7: 5.3M bank conflicts, +40MB FETCH) — do not revisit without asm.
__global__ __launch_bounds__(256) void k_gemm2(
    const ushort_t* __restrict__ h, const ushort_t* __restrict__ Wt,
    const float* __restrict__ b2, const float* __restrict__ topp,
    const float* __restrict__ Wv, const int* __restrict__ meta,
    const int* __restrict__ tiles, const int* __restrict__ slot_token,
    float* __restrict__ outf, float* __restrict__ v) {
  __shared__ ushort_t As[64 * 64];  // 8 KB
  __shared__ ushort_t Bs[64 * 64];  // 8 KB
  if ((int)blockIdx.x >= meta[0]) return;
  int desc = tiles[blockIdx.x];
  int e = desc >> 16;
  int slot0 = (desc & 0xFFFF) + ((int)blockIdx.z << 6);  // 64-row half
  int n0 = blockIdx.y * 64;          // 12 n-blocks
  int tid = threadIdx.x;
  int lane = tid & 63, w = tid >> 6;
  int mq = (w & 1) << 5;   // 0 / 32
  int nq = (w >> 1) << 5;  // 0 / 32
  int mrow = lane & 15, quad = lane >> 4;
  int rl = tid >> 3;                  // row 0..31 (+32 per round)
  int sw = (tid & 7) ^ (rl & 7);      // pre-swizzled global chunk
  const ushort_t* Ag = h + (size_t)(slot0 + rl) * 3072 + sw * 8;
  const ushort_t* Bg = Wt + ((size_t)e * 768 + n0 + rl) * 3072 + sw * 8;
  facc4 acc[2][2];
  facc4 zero = {0.f, 0.f, 0.f, 0.f};
#pragma unroll
  for (int i = 0; i < 2; ++i)
#pragma unroll
    for (int j = 0; j < 2; ++j) acc[i][j] = zero;
  for (int k0 = 0; k0 < 3072; k0 += 64) {
#pragma unroll
    for (int r = 0; r < 2; ++r) {
      GL2LDS(Ag + k0 + (size_t)r * 32 * 3072, As + (r * 256 + tid) * 8);
      GL2LDS(Bg + k0 + (size_t)r * 32 * 3072, Bs + (r * 256 + tid) * 8);
    }
    __syncthreads();
#pragma unroll
    for (int kk = 0; kk < 2; ++kk) {
      bfrag8 a[2], b[2];
      int ph = (((kk << 2) + quad) ^ (mrow & 7)) << 3;
#pragma unroll
      for (int i = 0; i < 2; ++i)
        a[i] = *(const bfrag8*)(As + ((mq + i * 16 + mrow) << 6) + ph);
#pragma unroll
      for (int j = 0; j < 2; ++j)
        b[j] = *(const bfrag8*)(Bs + ((nq + j * 16 + mrow) << 6) + ph);
#pragma unroll
      for (int i = 0; i < 2; ++i)
#pragma unroll
        for (int j = 0; j < 2; ++j)
          acc[i][j] = __builtin_amdgcn_mfma_f32_16x16x32_bf16(a[i], b[j],
                                                              acc[i][j], 0, 0, 0);
    }
    __syncthreads();
  }
  const float* bb = b2 + (size_t)e * 768 + n0;
  float wv0 = Wv[n0 + nq + mrow];
  float wv1 = Wv[n0 + nq + 16 + mrow];
  float bb0 = bb[nq + mrow], bb1 = bb[nq + 16 + mrow];
#pragma unroll
  for (int i = 0; i < 2; ++i) {
    int mo = mq + i * 16 + (quad << 2);
#pragma unroll
    for (int r = 0; r < 4; ++r) {
      int slot = slot0 + mo + r;
      int tok = slot_token[slot];  // uniform within 16-lane quad segment
      if (tok < 0) continue;
      float tp = topp[tok];
      float f0 = tp * (acc[i][0][r] + bb0);
      float f1 = tp * (acc[i][1][r] + bb1);
      outf[(size_t)tok * 768 + n0 + nq + mrow] = f0;
      outf[(size_t)tok * 768 + n0 + nq + 16 + mrow] = f1;
      float pv = f0 * wv0 + f1 * wv1;
#pragma unroll
      for (int off = 8; off > 0; off >>= 1) pv += __shfl_down(pv, off, 16);
      if (mrow == 0) atomicAdd(&v[tok], pv);
    }
  }
}

// ---------------- BK parallel scan: Mobius matrices, 3-level scan ---------------
struct CM {
  float ar, ai, br, bi, cr, ci, dr, di;  // [[a,b],[c,d]] complex
};
__device__ __forceinline__ CM cmmul(const CM& A, const CM& B) {  // A*B
  CM C;
  C.ar = A.ar * B.ar - A.ai * B.ai + A.br * B.cr - A.bi * B.ci;
  C.ai = A.ar * B.ai + A.ai * B.ar + A.br * B.ci + A.bi * B.cr;
  C.br = A.ar * B.br - A.ai * B.bi + A.br * B.dr - A.bi * B.di;
  C.bi = A.ar * B.bi + A.ai * B.br + A.br * B.di + A.bi * B.dr;
  C.cr = A.cr * B.ar - A.ci * B.ai + A.dr * B.cr - A.di * B.ci;
  C.ci = A.cr * B.ai + A.ci * B.ar + A.dr * B.ci + A.di * B.cr;
  C.dr = A.cr * B.br - A.ci * B.bi + A.dr * B.dr - A.di * B.di;
  C.di = A.cr * B.bi + A.ci * B.br + A.dr * B.di + A.di * B.dr;
  return C;
}
__device__ __forceinline__ void cmnorm(CM& A) {
  float m = fmaxf(fmaxf(fmaxf(fabsf(A.ar), fabsf(A.ai)),
                        fmaxf(fabsf(A.br), fabsf(A.bi))),
                  fmaxf(fmaxf(fabsf(A.cr), fabsf(A.ci)),
                        fmaxf(fabsf(A.dr), fabsf(A.di))));
  float s = 1.0f / fmaxf(m, 1e-30f);
  A.ar *= s; A.ai *= s; A.br *= s; A.bi *= s;
  A.cr *= s; A.ci *= s; A.dr *= s; A.di *= s;
}
__device__ __forceinline__ CM cmshfl_up(const CM& A, int off) {
  CM B;
  B.ar = __shfl_up(A.ar, off, 64); B.ai = __shfl_up(A.ai, off, 64);
  B.br = __shfl_up(A.br, off, 64); B.bi = __shfl_up(A.bi, off, 64);
  B.cr = __shfl_up(A.cr, off, 64); B.ci = __shfl_up(A.ci, off, 64);
  B.dr = __shfl_up(A.dr, off, 64); B.di = __shfl_up(A.di, off, 64);
  return B;
}

__global__ __launch_bounds__(256) void k_bkscan(
    const float* __restrict__ v, float* __restrict__ Ar, float* __restrict__ Ai,
    float* __restrict__ Br, float* __restrict__ Bi) {
  int b = blockIdx.x >> 1, rev = blockIdx.x & 1;
  int tid = threadIdx.x, lane = tid & 63, wv = tid >> 6;
  const float* vb = v + b * SEQ;
  float dv[8];
  int sbase = tid * 8;
#pragma unroll
  for (int q = 0; q < 8; ++q) {
    int s = sbase + q;
    int n = rev ? (SEQ - 1 - s) : s;
    dv[q] = fminf(3.f, fmaxf(-3.f, vb[n]));
  }
  CM L;
  L.ar = dv[0]; L.ai = -1.f; L.br = -1.f; L.bi = 0.f;
  L.cr = 1.f; L.ci = 0.f; L.dr = 0.f; L.di = 0.f;
#pragma unroll
  for (int q = 1; q < 8; ++q) {
    float dr = dv[q];
    float nar = dr * L.ar + L.ai - L.cr;
    float nai = dr * L.ai - L.ar - L.ci;
    float nbr = dr * L.br + L.bi - L.dr;
    float nbi = dr * L.bi - L.br - L.di;
    L.cr = L.ar; L.ci = L.ai; L.dr = L.br; L.di = L.bi;
    L.ar = nar; L.ai = nai; L.br = nbr; L.bi = nbi;
  }
  cmnorm(L);
  CM I = L;
#pragma unroll
  for (int off = 1; off < 64; off <<= 1) {
    CM P = cmshfl_up(I, off);
    if (lane >= off) {
      I = cmmul(I, P);
      cmnorm(I);
    }
  }
  __shared__ float wag[4][8];
  if (lane == 63) {
    wag[wv][0] = I.ar; wag[wv][1] = I.ai; wag[wv][2] = I.br; wag[wv][3] = I.bi;
    wag[wv][4] = I.cr; wag[wv][5] = I.ci; wag[wv][6] = I.dr; wag[wv][7] = I.di;
  }
  __syncthreads();
  CM E = cmshfl_up(I, 1);
  if (lane == 0) {
    E.ar = 1.f; E.ai = 0.f; E.br = 0.f; E.bi = 0.f;
    E.cr = 0.f; E.ci = 0.f; E.dr = 1.f; E.di = 0.f;
  }
  for (int j = wv - 1; j >= 0; --j) {
    CM Aj;
    Aj.ar = wag[j][0]; Aj.ai = wag[j][1]; Aj.br = wag[j][2]; Aj.bi = wag[j][3];
    Aj.cr = wag[j][4]; Aj.ci = wag[j][5]; Aj.dr = wag[j][6]; Aj.di = wag[j][7];
    E = cmmul(E, Aj);
    cmnorm(E);
  }
  float u0r = E.ar, u0i = E.ai, u1r = E.cr, u1i = E.ci;
  float* Rr = rev ? Br : Ar;
  float* Ri = rev ? Bi : Ai;
#pragma unroll
  for (int q = 0; q < 8; ++q) {
    float dr = dv[q];
    float n0r = dr * u0r + u0i - u1r;
    float n0i = dr * u0i - u0r - u1i;
    u1r = u0r; u1i = u0i; u0r = n0r; u0i = n0i;
    float m = fmaxf(fmaxf(fabsf(u0r), fabsf(u0i)), fmaxf(fabsf(u1r), fabsf(u1i)));
    float sc = 1.f / fmaxf(m, 1e-30f);
    u0r *= sc; u0i *= sc; u1r *= sc; u1i *= sc;
    float den = u1r * u1r + u1i * u1i;
    float arr = (u0r * u1r + u0i * u1i) / den;
    float aii = (u0i * u1r - u0r * u1i) / den;
    int s = sbase + q;
    int n = rev ? (SEQ - 1 - s) : s;
    Rr[b * SEQ + n] = arr;
    Ri[b * SEQ + n] = aii;
  }
}

// ---------------- final (in place on d_out): out += bk_scale*(feats@Wo+bo) ------
__global__ __launch_bounds__(256) void k_final(
    float* __restrict__ outf, const float* __restrict__ v,
    const float* __restrict__ Ar, const float* __restrict__ Ai,
    const float* __restrict__ Br, const float* __restrict__ Bi,
    const float* __restrict__ score, const float* __restrict__ thr,
    const float* __restrict__ Wo, const float* __restrict__ bo,
    const float* __restrict__ bk) {
  int t = blockIdx.x;
  int b = t >> 11;
  float vc = fminf(3.f, fmaxf(-3.f, v[t]));
  float cr = Ar[t] + Br[t] - vc;
  float ci = Ai[t] + Bi[t] + 1.f;
  float den = cr * cr + ci * ci;
  float gr = cr / den, gi = -ci / den;
  bool m = (score[t] >= thr[b]);
  float fr = m ? fminf(10.f, fmaxf(-10.f, gr)) : 0.f;
  float fi = m ? fminf(10.f, fmaxf(-10.f, gi)) : 0.f;
  float bs = bk[0];
  for (int d = threadIdx.x; d < DDIM; d += 256) {
    float o = outf[(size_t)t * DDIM + d] +
              bs * (fr * Wo[d] + fi * Wo[DDIM + d] + bo[d]);
    outf[(size_t)t * DDIM + d] = o;
  }
}

extern "C" void kernel_launch(void* const* d_in, const int* in_sizes, int n_in,
                              void* d_out, int out_size, void* d_ws, size_t ws_size,
                              hipStream_t stream) {
  const float* x  = (const float*)d_in[0];
  const float* Wg = (const float*)d_in[1];
  const float* bg = (const float*)d_in[2];
  const float* W1 = (const float*)d_in[3];
  const float* b1 = (const float*)d_in[4];
  const float* W2 = (const float*)d_in[5];
  const float* b2 = (const float*)d_in[6];
  const float* Wv = (const float*)d_in[7];
  const float* bv = (const float*)d_in[8];
  const float* Wm = (const float*)d_in[9];
  const float* bm = (const float*)d_in[10];
  const float* Wo = (const float*)d_in[11];
  const float* bo = (const float*)d_in[12];
  const float* bk = (const float*)d_in[13];
  float* outf = (float*)d_out;

  unsigned char* w = (unsigned char*)d_ws;
  int*   expert     = (int*)(w + 0);
  float* topp       = (float*)(w + 16384);
  float* score      = (float*)(w + 32768);
  float* v          = (float*)(w + 49152);
  float* Ar         = (float*)(w + 65536);
  float* Ai         = (float*)(w + 81920);
  float* Br         = (float*)(w + 98304);
  float* Bi         = (float*)(w + 114688);
  float* thr        = (float*)(w + 131072);
  int*   meta       = (int*)(w + 131104);
  int*   tiles      = (int*)(w + 131136);
  int*   slot_token = (int*)(w + 131328);            // 5120 ints
  ushort_t* xp      = (ushort_t*)(w + 152064);       // 5120*768  bf16 = 7.9 MB
  ushort_t* h       = (ushort_t*)(w + 8016384);      // 5120*3072 bf16 = 31.5 MB
  ushort_t* W1t     = (ushort_t*)(w + 39473664);     // 8*3072*768 bf16 = 37.7 MB
  // optional separate W2t right after W1t (fused path): +37.7 MB -> ~115 MB total
  size_t w2t_off = 39473664ull + 37748736ull;        // 77222400
  size_t need    = w2t_off + 37748736ull;            // 114971136
  bool fused = (ws_size >= need);
  ushort_t* W2t = fused ? (ushort_t*)(w + w2t_off) : W1t;

  k_gate<<<1024, 256, 0, stream>>>(x, Wg, bg, Wm, bm, bv, expert, topp, score, v);
  k_thrbucket<<<3, 256, 0, stream>>>(score, thr, expert, meta, tiles, slot_token);

  if (fused) {
    // xgather (5120) + W1T (4608) + W2T (4608) in one launch: W2 transpose
    // overlaps with the rest instead of serializing between gemm1 and gemm2
    k_prep<<<MAXSLOTS + 9216, 256, 0, stream>>>(x, slot_token, xp, W1, W1t, W2,
                                                W2t);
    k_gemm1<<<dim3(MAXTILES, 24), 256, 0, stream>>>(xp, W1t, b1, meta, tiles, h);
    k_gemm2<<<dim3(MAXTILES, 12, 2), 256, 0, stream>>>(h, W2t, b2, topp, Wv,
                                                       meta, tiles, slot_token,
                                                       outf, v);
  } else {
    // fallback: round-5 sequence, W1t buffer reused for W2t after gemm1
    k_prep<<<MAXSLOTS + 4608, 256, 0, stream>>>(x, slot_token, xp, W1, W1t, W2,
                                                W2t);
    k_gemm1<<<dim3(MAXTILES, 24), 256, 0, stream>>>(xp, W1t, b1, meta, tiles, h);
    k_wt<<<4608, 256, 0, stream>>>(W2, W1t, 3072, 768, 48);
    k_gemm2<<<dim3(MAXTILES, 12, 2), 256, 0, stream>>>(h, W1t, b2, topp, Wv,
                                                       meta, tiles, slot_token,
                                                       outf, v);
  }

  k_bkscan<<<4, 256, 0, stream>>>(v, Ar, Ai, Br, Bi);
  k_final<<<NTOK, 256, 0, stream>>>(outf, v, Ar, Ai, Br, Bi, score, thr, Wo, bo, bk);
}

// Round 9
// 326.402 us; speedup vs baseline: 1.1281x; 1.0265x over previous
//
#include <hip/hip_runtime.h>

typedef unsigned short ushort_t;
typedef unsigned int uint32;

#define NTOK 4096
#define SEQ 2048
#define DDIM 768
#define HDIM 3072
#define NEXP 8
#define KKEEP 819
#define MTILE 128
#define MAXTILES 40
#define MAXSLOTS 5120
#define NB1 (MAXTILES * 24)  // gemm1 compute blocks in flattened grid

typedef __attribute__((ext_vector_type(8))) short bfrag8;   // 8 bf16 (4 VGPRs)
typedef __attribute__((ext_vector_type(4))) float facc4;    // 4 fp32 acc

__device__ __forceinline__ ushort_t f2bf(float f) {
  uint32 x = __float_as_uint(f);
  uint32 r = (x + 0x7FFFu + ((x >> 16) & 1u)) >> 16;
  return (ushort_t)r;
}
// gelu = 0.5u(1+tanh(z)) = u / (1 + e^{-2z}), z = 0.79788456(u+0.044715u^3)
// exp2-based: branchless v_exp_f32 + v_rcp_f32 (~8 VALU ops vs ocml tanhf ~60)
__device__ __forceinline__ float gelu_f(float u) {
  float z = u + 0.044715f * u * u * u;
  float e = __builtin_amdgcn_exp2f(-2.3021840216f * z);  // 2*0.79788456*log2(e)
  return u * __builtin_amdgcn_rcpf(1.f + e);
}

// async global->LDS, 16 bytes per lane, LDS dest contiguous in lane order
#define GL2LDS(gp, lp)                                                        \
  __builtin_amdgcn_global_load_lds(                                           \
      (const __attribute__((address_space(1))) void*)(gp),                    \
      (__attribute__((address_space(3))) void*)(lp), 16, 0, 0)

// shared transpose body: fp32 [e][K][N] 64x64 tile -> bf16 [e][N][K]
__device__ __forceinline__ void wtile_transpose(const float* __restrict__ src,
                                                ushort_t* __restrict__ dst,
                                                int K, int N, int nkb, int bi,
                                                int tid, float (*t)[65]) {
  int per_e = nkb * (N / 64);
  int e = bi / per_e, rem = bi % per_e;
  int k0 = (rem % nkb) * 64, n0 = (rem / nkb) * 64;
  const float* S = src + (size_t)e * K * N;
  ushort_t* D = dst + (size_t)e * N * K;
  int r = tid >> 4, c4 = (tid & 15) * 4;
#pragma unroll
  for (int it = 0; it < 4; ++it) {
    int k = r + it * 16;
    float4 vv = *(const float4*)(S + (size_t)(k0 + k) * N + n0 + c4);
    t[k][c4] = vv.x; t[k][c4 + 1] = vv.y; t[k][c4 + 2] = vv.z; t[k][c4 + 3] = vv.w;
  }
  __syncthreads();
#pragma unroll
  for (int it = 0; it < 4; ++it) {
    int n = r + it * 16;
    ushort4 o;
    o.x = f2bf(t[c4][n]); o.y = f2bf(t[c4 + 1][n]);
    o.z = f2bf(t[c4 + 2][n]); o.w = f2bf(t[c4 + 3][n]);
    *(ushort4*)(D + (size_t)(n0 + n) * K + k0 + c4) = o;
  }
}

// ---------------- gate (bx<1024) + W1 transpose (bx>=1024) ----------------------
// W1T depends only on W1 -> overlap it with the gate instead of serializing
// before gemm1. Launch boundary guarantees W1t complete before k_gemm1.
__global__ __launch_bounds__(256) void k_gate(
    const float* __restrict__ x, const float* __restrict__ Wg,
    const float* __restrict__ bg, const float* __restrict__ Wm,
    const float* __restrict__ bm, const float* __restrict__ bv,
    int* __restrict__ expert, float* __restrict__ topp,
    float* __restrict__ score, float* __restrict__ v,
    const float* __restrict__ W1, ushort_t* __restrict__ W1t) {
  __shared__ float ts[64][65];
  int tid = threadIdx.x;
  if ((int)blockIdx.x >= 1024) {
    wtile_transpose(W1, W1t, 768, 3072, 12, (int)blockIdx.x - 1024, tid, ts);
    return;
  }
  int lane = tid & 63, w = tid >> 6;
  int t = blockIdx.x * 4 + w;
  float g[8];
#pragma unroll
  for (int e = 0; e < 8; ++e) g[e] = 0.f;
  float sm = 0.f;
  for (int d = lane; d < DDIM; d += 64) {
    float xv = x[(size_t)t * DDIM + d];
    float4 w0 = *(const float4*)(Wg + d * 8);
    float4 w1 = *(const float4*)(Wg + d * 8 + 4);
    g[0] += xv * w0.x; g[1] += xv * w0.y; g[2] += xv * w0.z; g[3] += xv * w0.w;
    g[4] += xv * w1.x; g[5] += xv * w1.y; g[6] += xv * w1.z; g[7] += xv * w1.w;
    sm += xv * Wm[d];
  }
#pragma unroll
  for (int e = 0; e < 8; ++e) {
#pragma unroll
    for (int off = 32; off > 0; off >>= 1) g[e] += __shfl_down(g[e], off, 64);
  }
#pragma unroll
  for (int off = 32; off > 0; off >>= 1) sm += __shfl_down(sm, off, 64);
  if (lane == 0) {
    float l[8];
#pragma unroll
    for (int e = 0; e < 8; ++e) l[e] = g[e] + bg[e];
    int am = 0;
    float mx = l[0];
#pragma unroll
    for (int e = 1; e < 8; ++e) {
      if (l[e] > mx) { mx = l[e]; am = e; }  // first-max = jnp.argmax
    }
    float s = 0.f;
#pragma unroll
    for (int e = 0; e < 8; ++e) s += expf(l[e] - mx);
    expert[t] = am;
    topp[t] = 1.f / s;
    float z = sm + bm[0];
    score[t] = 1.f / (1.f + expf(-z));
    v[t] = bv[0];  // init for gemm2's fused vdot atomic accumulation
  }
}

// ---------------- merged: histogram top-K threshold (b<2) + bucket (b==2) -------
__global__ __launch_bounds__(256) void k_thrbucket(
    const float* __restrict__ score, float* __restrict__ thr,
    const int* __restrict__ expert, int* __restrict__ meta,
    int* __restrict__ tiles, int* __restrict__ slot_token) {
  int tid = threadIdx.x;
  if (blockIdx.x < 2) {
    int b = blockIdx.x;
    __shared__ uint32 chist[256];
    __shared__ float vals[2048];
    __shared__ uint32 scnt;
    __shared__ int bstar_s, kprime_s;
    chist[tid] = 0;
    if (tid == 0) scnt = 0;
    __syncthreads();
    for (int i = tid; i < SEQ; i += 256) {
      float s = score[b * SEQ + i];
      int bin = min(255, max(0, (int)(s * 256.f)));
      atomicAdd(&chist[bin], 1u);
    }
    __syncthreads();
    if (tid == 0) {
      int cum = 0;
      for (int j = 255; j >= 0; --j) {
        cum += (int)chist[j];
        if (cum >= KKEEP) {
          bstar_s = j;
          kprime_s = KKEEP - (cum - (int)chist[j]);
          break;
        }
      }
    }
    __syncthreads();
    int bstar = bstar_s, kprime = kprime_s;
    for (int i = tid; i < SEQ; i += 256) {
      float s = score[b * SEQ + i];
      int bin = min(255, max(0, (int)(s * 256.f)));
      if (bin == bstar) vals[atomicAdd(&scnt, 1u)] = s;
    }
    __syncthreads();
    int n = (int)scnt;
    for (int ci = tid; ci < n; ci += 256) {
      float xx = vals[ci];
      int g = 0, eq = 0;
      for (int j = 0; j < n; ++j) {
        g += (vals[j] > xx);
        eq += (vals[j] == xx);
      }
      if (g < kprime && kprime <= g + eq) thr[b] = xx;  // exact K-th largest
    }
  } else {
    __shared__ int cnt[NEXP];
    __shared__ int off[NEXP];
    if (tid < NEXP) cnt[tid] = 0;
    __syncthreads();
    for (int t = tid; t < NTOK; t += 256) atomicAdd(&cnt[expert[t]], 1);
    __syncthreads();
    if (tid == 0) {
      int run = 0, nt = 0;
      for (int e = 0; e < NEXP; ++e) {
        off[e] = run;
        int c = cnt[e];
        int padded = (c + MTILE - 1) / MTILE * MTILE;
        for (int s = 0; s < padded; s += MTILE)
          tiles[nt++] = (e << 16) | (run + s);
        run += padded;
      }
      meta[0] = nt;
      meta[1] = run;
    }
    __syncthreads();
    for (int s = tid; s < MAXSLOTS; s += 256) slot_token[s] = -1;
    __syncthreads();
    for (int t = tid; t < NTOK; t += 256) {
      int p = atomicAdd(&off[expert[t]], 1);
      slot_token[p] = t;
    }
  }
}

// ---------------- x-gather only (transposes moved to k_gate / k_gemm1) ----------
__global__ __launch_bounds__(256) void k_prep(
    const float* __restrict__ x, const int* __restrict__ slot_token,
    ushort_t* __restrict__ xp) {
  int bx = blockIdx.x;
  int tid = threadIdx.x;
  int tok = slot_token[bx];
  for (int d = tid; d < DDIM; d += 256) {
    float vv = (tok >= 0) ? x[(size_t)tok * DDIM + d] : 0.f;
    xp[(size_t)bx * DDIM + d] = f2bf(vv);
  }
}

// standalone weight transpose (W2) — fallback when workspace too small to fuse
__global__ __launch_bounds__(256) void k_wt(const float* __restrict__ src,
                                            ushort_t* __restrict__ dst, int K,
                                            int N, int nkb) {
  __shared__ float t[64][65];
  wtile_transpose(src, dst, K, N, nkb, blockIdx.x, threadIdx.x, t);
}

// ---------------- gemm1 (bid<NB1) + W2 transpose (bid>=NB1, fused path) ---------
// Round-5 proven gemm config: 128x128 tile, BK=64, coalesced staging, chunk-XOR
// swizzle, 0 conflicts. W2T blocks at grid tail fill idle CU slots and overlap
// the (memory-bound) transpose with the (latency-bound) gemm; W2t is consumed
// only by k_gemm2, ordered by the launch boundary. LDS unioned (32 KB).
__global__ __launch_bounds__(256) void k_gemm1(
    const ushort_t* __restrict__ xp, const ushort_t* __restrict__ Wt,
    const float* __restrict__ b1, const int* __restrict__ meta,
    const int* __restrict__ tiles, ushort_t* __restrict__ h,
    const float* __restrict__ W2, ushort_t* __restrict__ W2t) {
  __shared__ ushort_t smem[16384];  // 32 KB: As|Bs for gemm, t[64][65] for W2T
  int tid = threadIdx.x;
  int bid = blockIdx.x;
  if (bid >= NB1) {
    wtile_transpose(W2, W2t, 3072, 768, 48, bid - NB1,
                    tid, reinterpret_cast<float(*)[65]>(smem));
    return;
  }
  ushort_t* As = smem;          // 128*64
  ushort_t* Bs = smem + 8192;   // 128*64
  int tile = bid % MAXTILES, ny = bid / MAXTILES;  // tile-fast (old 2D order)
  if (tile >= meta[0]) return;
  int desc = tiles[tile];
  int e = desc >> 16, slot0 = desc & 0xFFFF;
  int n0 = ny * 128;
  int lane = tid & 63, w = tid >> 6;
  int mq = (w & 1) << 6, nq = (w >> 1) << 6;
  int mrow = lane & 15, quad = lane >> 4;
  int rl = tid >> 3;                  // row 0..31 (+32 per round)
  int sw = (tid & 7) ^ (rl & 7);      // pre-swizzled global chunk
  const ushort_t* Ag = xp + (size_t)(slot0 + rl) * 768 + sw * 8;
  const ushort_t* Bg = Wt + ((size_t)e * 3072 + n0 + rl) * 768 + sw * 8;
  facc4 acc[4][4];
  facc4 zero = {0.f, 0.f, 0.f, 0.f};
#pragma unroll
  for (int i = 0; i < 4; ++i)
#pragma unroll
    for (int j = 0; j < 4; ++j) acc[i][j] = zero;
  for (int k0 = 0; k0 < 768; k0 += 64) {
#pragma unroll
    for (int r = 0; r < 4; ++r) {
      GL2LDS(Ag + k0 + (size_t)r * 32 * 768, As + (r * 256 + tid) * 8);
      GL2LDS(Bg + k0 + (size_t)r * 32 * 768, Bs + (r * 256 + tid) * 8);
    }
    __syncthreads();
#pragma unroll
    for (int kk = 0; kk < 2; ++kk) {
      bfrag8 a[4], b[4];
      int ph = (((kk << 2) + quad) ^ (mrow & 7)) << 3;
#pragma unroll
      for (int i = 0; i < 4; ++i)
        a[i] = *(const bfrag8*)(As + ((mq + i * 16 + mrow) << 6) + ph);
#pragma unroll
      for (int j = 0; j < 4; ++j)
        b[j] = *(const bfrag8*)(Bs + ((nq + j * 16 + mrow) << 6) + ph);
#pragma unroll
      for (int i = 0; i < 4; ++i)
#pragma unroll
        for (int j = 0; j < 4; ++j)
          acc[i][j] = __builtin_amdgcn_mfma_f32_16x16x32_bf16(a[i], b[j],
                                                              acc[i][j], 0, 0, 0);
    }
    __syncthreads();
  }
  const float* bb = b1 + (size_t)e * 3072 + n0;
#pragma unroll
  for (int i = 0; i < 4; ++i) {
    int mo = mq + i * 16 + (quad << 2);
#pragma unroll
    for (int j = 0; j < 4; ++j) {
      int nc = nq + j * 16 + mrow;
      float bias = bb[nc];
#pragma unroll
      for (int r = 0; r < 4; ++r) {
        float val = gelu_f(acc[i][j][r] + bias);
        h[(size_t)(slot0 + mo + r) * 3072 + n0 + nc] = f2bf(val);
      }
    }
  }
}

// ---------------- grouped MFMA GEMM layer 2 + fused vdot ------------------------
// Round-5 proven config: M-split x2 (64x64 tile, 960 blocks ~3.75/CU), BK=64,
// [row][64] LDS + 3-bit chunk-XOR (0 conflicts). BK=128 regressed (round 7:
// 5.3M bank conflicts, +40MB FETCH) — do not revisit without asm.
__global__ __launch_bounds__(256) void k_gemm2(
    const ushort_t* __restrict__ h, const ushort_t* __restrict__ Wt,
    const float* __restrict__ b2, const float* __restrict__ topp,
    const float* __restrict__ Wv, const int* __restrict__ meta,
    const int* __restrict__ tiles, const int* __restrict__ slot_token,
    float* __restrict__ outf, float* __restrict__ v) {
  __shared__ ushort_t As[64 * 64];  // 8 KB
  __shared__ ushort_t Bs[64 * 64];  // 8 KB
  if ((int)blockIdx.x >= meta[0]) return;
  int desc = tiles[blockIdx.x];
  int e = desc >> 16;
  int slot0 = (desc & 0xFFFF) + ((int)blockIdx.z << 6);  // 64-row half
  int n0 = blockIdx.y * 64;          // 12 n-blocks
  int tid = threadIdx.x;
  int lane = tid & 63, w = tid >> 6;
  int mq = (w & 1) << 5;   // 0 / 32
  int nq = (w >> 1) << 5;  // 0 / 32
  int mrow = lane & 15, quad = lane >> 4;
  int rl = tid >> 3;                  // row 0..31 (+32 per round)
  int sw = (tid & 7) ^ (rl & 7);      // pre-swizzled global chunk
  const ushort_t* Ag = h + (size_t)(slot0 + rl) * 3072 + sw * 8;
  const ushort_t* Bg = Wt + ((size_t)e * 768 + n0 + rl) * 3072 + sw * 8;
  facc4 acc[2][2];
  facc4 zero = {0.f, 0.f, 0.f, 0.f};
#pragma unroll
  for (int i = 0; i < 2; ++i)
#pragma unroll
    for (int j = 0; j < 2; ++j) acc[i][j] = zero;
  for (int k0 = 0; k0 < 3072; k0 += 64) {
#pragma unroll
    for (int r = 0; r < 2; ++r) {
      GL2LDS(Ag + k0 + (size_t)r * 32 * 3072, As + (r * 256 + tid) * 8);
      GL2LDS(Bg + k0 + (size_t)r * 32 * 3072, Bs + (r * 256 + tid) * 8);
    }
    __syncthreads();
#pragma unroll
    for (int kk = 0; kk < 2; ++kk) {
      bfrag8 a[2], b[2];
      int ph = (((kk << 2) + quad) ^ (mrow & 7)) << 3;
#pragma unroll
      for (int i = 0; i < 2; ++i)
        a[i] = *(const bfrag8*)(As + ((mq + i * 16 + mrow) << 6) + ph);
#pragma unroll
      for (int j = 0; j < 2; ++j)
        b[j] = *(const bfrag8*)(Bs + ((nq + j * 16 + mrow) << 6) + ph);
#pragma unroll
      for (int i = 0; i < 2; ++i)
#pragma unroll
        for (int j = 0; j < 2; ++j)
          acc[i][j] = __builtin_amdgcn_mfma_f32_16x16x32_bf16(a[i], b[j],
                                                              acc[i][j], 0, 0, 0);
    }
    __syncthreads();
  }
  const float* bb = b2 + (size_t)e * 768 + n0;
  float wv0 = Wv[n0 + nq + mrow];
  float wv1 = Wv[n0 + nq + 16 + mrow];
  float bb0 = bb[nq + mrow], bb1 = bb[nq + 16 + mrow];
#pragma unroll
  for (int i = 0; i < 2; ++i) {
    int mo = mq + i * 16 + (quad << 2);
#pragma unroll
    for (int r = 0; r < 4; ++r) {
      int slot = slot0 + mo + r;
      int tok = slot_token[slot];  // uniform within 16-lane quad segment
      if (tok < 0) continue;
      float tp = topp[tok];
      float f0 = tp * (acc[i][0][r] + bb0);
      float f1 = tp * (acc[i][1][r] + bb1);
      outf[(size_t)tok * 768 + n0 + nq + mrow] = f0;
      outf[(size_t)tok * 768 + n0 + nq + 16 + mrow] = f1;
      float pv = f0 * wv0 + f1 * wv1;
#pragma unroll
      for (int off = 8; off > 0; off >>= 1) pv += __shfl_down(pv, off, 16);
      if (mrow == 0) atomicAdd(&v[tok], pv);
    }
  }
}

// ---------------- BK parallel scan: Mobius matrices, 3-level scan ---------------
struct CM {
  float ar, ai, br, bi, cr, ci, dr, di;  // [[a,b],[c,d]] complex
};
__device__ __forceinline__ CM cmmul(const CM& A, const CM& B) {  // A*B
  CM C;
  C.ar = A.ar * B.ar - A.ai * B.ai + A.br * B.cr - A.bi * B.ci;
  C.ai = A.ar * B.ai + A.ai * B.ar + A.br * B.ci + A.bi * B.cr;
  C.br = A.ar * B.br - A.ai * B.bi + A.br * B.dr - A.bi * B.di;
  C.bi = A.ar * B.bi + A.ai * B.br + A.br * B.di + A.bi * B.dr;
  C.cr = A.cr * B.ar - A.ci * B.ai + A.dr * B.cr - A.di * B.ci;
  C.ci = A.cr * B.ai + A.ci * B.ar + A.dr * B.ci + A.di * B.cr;
  C.dr = A.cr * B.br - A.ci * B.bi + A.dr * B.dr - A.di * B.di;
  C.di = A.cr * B.bi + A.ci * B.br + A.dr * B.di + A.di * B.dr;
  return C;
}
__device__ __forceinline__ void cmnorm(CM& A) {
  float m = fmaxf(fmaxf(fmaxf(fabsf(A.ar), fabsf(A.ai)),
                        fmaxf(fabsf(A.br), fabsf(A.bi))),
                  fmaxf(fmaxf(fabsf(A.cr), fabsf(A.ci)),
                        fmaxf(fabsf(A.dr), fabsf(A.di))));
  float s = 1.0f / fmaxf(m, 1e-30f);
  A.ar *= s; A.ai *= s; A.br *= s; A.bi *= s;
  A.cr *= s; A.ci *= s; A.dr *= s; A.di *= s;
}
__device__ __forceinline__ CM cmshfl_up(const CM& A, int off) {
  CM B;
  B.ar = __shfl_up(A.ar, off, 64); B.ai = __shfl_up(A.ai, off, 64);
  B.br = __shfl_up(A.br, off, 64); B.bi = __shfl_up(A.bi, off, 64);
  B.cr = __shfl_up(A.cr, off, 64); B.ci = __shfl_up(A.ci, off, 64);
  B.dr = __shfl_up(A.dr, off, 64); B.di = __shfl_up(A.di, off, 64);
  return B;
}

__global__ __launch_bounds__(256) void k_bkscan(
    const float* __restrict__ v, float* __restrict__ Ar, float* __restrict__ Ai,
    float* __restrict__ Br, float* __restrict__ Bi) {
  int b = blockIdx.x >> 1, rev = blockIdx.x & 1;
  int tid = threadIdx.x, lane = tid & 63, wv = tid >> 6;
  const float* vb = v + b * SEQ;
  float dv[8];
  int sbase = tid * 8;
#pragma unroll
  for (int q = 0; q < 8; ++q) {
    int s = sbase + q;
    int n = rev ? (SEQ - 1 - s) : s;
    dv[q] = fminf(3.f, fmaxf(-3.f, vb[n]));
  }
  CM L;
  L.ar = dv[0]; L.ai = -1.f; L.br = -1.f; L.bi = 0.f;
  L.cr = 1.f; L.ci = 0.f; L.dr = 0.f; L.di = 0.f;
#pragma unroll
  for (int q = 1; q < 8; ++q) {
    float dr = dv[q];
    float nar = dr * L.ar + L.ai - L.cr;
    float nai = dr * L.ai - L.ar - L.ci;
    float nbr = dr * L.br + L.bi - L.dr;
    float nbi = dr * L.bi - L.br - L.di;
    L.cr = L.ar; L.ci = L.ai; L.dr = L.br; L.di = L.bi;
    L.ar = nar; L.ai = nai; L.br = nbr; L.bi = nbi;
  }
  cmnorm(L);
  CM I = L;
#pragma unroll
  for (int off = 1; off < 64; off <<= 1) {
    CM P = cmshfl_up(I, off);
    if (lane >= off) {
      I = cmmul(I, P);
      cmnorm(I);
    }
  }
  __shared__ float wag[4][8];
  if (lane == 63) {
    wag[wv][0] = I.ar; wag[wv][1] = I.ai; wag[wv][2] = I.br; wag[wv][3] = I.bi;
    wag[wv][4] = I.cr; wag[wv][5] = I.ci; wag[wv][6] = I.dr; wag[wv][7] = I.di;
  }
  __syncthreads();
  CM E = cmshfl_up(I, 1);
  if (lane == 0) {
    E.ar = 1.f; E.ai = 0.f; E.br = 0.f; E.bi = 0.f;
    E.cr = 0.f; E.ci = 0.f; E.dr = 1.f; E.di = 0.f;
  }
  for (int j = wv - 1; j >= 0; --j) {
    CM Aj;
    Aj.ar = wag[j][0]; Aj.ai = wag[j][1]; Aj.br = wag[j][2]; Aj.bi = wag[j][3];
    Aj.cr = wag[j][4]; Aj.ci = wag[j][5]; Aj.dr = wag[j][6]; Aj.di = wag[j][7];
    E = cmmul(E, Aj);
    cmnorm(E);
  }
  float u0r = E.ar, u0i = E.ai, u1r = E.cr, u1i = E.ci;
  float* Rr = rev ? Br : Ar;
  float* Ri = rev ? Bi : Ai;
#pragma unroll
  for (int q = 0; q < 8; ++q) {
    float dr = dv[q];
    float n0r = dr * u0r + u0i - u1r;
    float n0i = dr * u0i - u0r - u1i;
    u1r = u0r; u1i = u0i; u0r = n0r; u0i = n0i;
    float m = fmaxf(fmaxf(fabsf(u0r), fabsf(u0i)), fmaxf(fabsf(u1r), fabsf(u1i)));
    float sc = 1.f / fmaxf(m, 1e-30f);
    u0r *= sc; u0i *= sc; u1r *= sc; u1i *= sc;
    float den = u1r * u1r + u1i * u1i;
    float arr = (u0r * u1r + u0i * u1i) / den;
    float aii = (u0i * u1r - u0r * u1i) / den;
    int s = sbase + q;
    int n = rev ? (SEQ - 1 - s) : s;
    Rr[b * SEQ + n] = arr;
    Ri[b * SEQ + n] = aii;
  }
}

// ---------------- final (in place on d_out): out += bk_scale*(feats@Wo+bo) ------
__global__ __launch_bounds__(256) void k_final(
    float* __restrict__ outf, const float* __restrict__ v,
    const float* __restrict__ Ar, const float* __restrict__ Ai,
    const float* __restrict__ Br, const float* __restrict__ Bi,
    const float* __restrict__ score, const float* __restrict__ thr,
    const float* __restrict__ Wo, const float* __restrict__ bo,
    const float* __restrict__ bk) {
  int t = blockIdx.x;
  int b = t >> 11;
  float vc = fminf(3.f, fmaxf(-3.f, v[t]));
  float cr = Ar[t] + Br[t] - vc;
  float ci = Ai[t] + Bi[t] + 1.f;
  float den = cr * cr + ci * ci;
  float gr = cr / den, gi = -ci / den;
  bool m = (score[t] >= thr[b]);
  float fr = m ? fminf(10.f, fmaxf(-10.f, gr)) : 0.f;
  float fi = m ? fminf(10.f, fmaxf(-10.f, gi)) : 0.f;
  float bs = bk[0];
  for (int d = threadIdx.x; d < DDIM; d += 256) {
    float o = outf[(size_t)t * DDIM + d] +
              bs * (fr * Wo[d] + fi * Wo[DDIM + d] + bo[d]);
    outf[(size_t)t * DDIM + d] = o;
  }
}

extern "C" void kernel_launch(void* const* d_in, const int* in_sizes, int n_in,
                              void* d_out, int out_size, void* d_ws, size_t ws_size,
                              hipStream_t stream) {
  const float* x  = (const float*)d_in[0];
  const float* Wg = (const float*)d_in[1];
  const float* bg = (const float*)d_in[2];
  const float* W1 = (const float*)d_in[3];
  const float* b1 = (const float*)d_in[4];
  const float* W2 = (const float*)d_in[5];
  const float* b2 = (const float*)d_in[6];
  const float* Wv = (const float*)d_in[7];
  const float* bv = (const float*)d_in[8];
  const float* Wm = (const float*)d_in[9];
  const float* bm = (const float*)d_in[10];
  const float* Wo = (const float*)d_in[11];
  const float* bo = (const float*)d_in[12];
  const float* bk = (const float*)d_in[13];
  float* outf = (float*)d_out;

  unsigned char* w = (unsigned char*)d_ws;
  int*   expert     = (int*)(w + 0);
  float* topp       = (float*)(w + 16384);
  float* score      = (float*)(w + 32768);
  float* v          = (float*)(w + 49152);
  float* Ar         = (float*)(w + 65536);
  float* Ai         = (float*)(w + 81920);
  float* Br         = (float*)(w + 98304);
  float* Bi         = (float*)(w + 114688);
  float* thr        = (float*)(w + 131072);
  int*   meta       = (int*)(w + 131104);
  int*   tiles      = (int*)(w + 131136);
  int*   slot_token = (int*)(w + 131328);            // 5120 ints
  ushort_t* xp      = (ushort_t*)(w + 152064);       // 5120*768  bf16 = 7.9 MB
  ushort_t* h       = (ushort_t*)(w + 8016384);      // 5120*3072 bf16 = 31.5 MB
  ushort_t* W1t     = (ushort_t*)(w + 39473664);     // 8*3072*768 bf16 = 37.7 MB
  // optional separate W2t right after W1t (fused path): +37.7 MB -> ~115 MB total
  size_t w2t_off = 39473664ull + 37748736ull;        // 77222400
  size_t need    = w2t_off + 37748736ull;            // 114971136
  bool fused = (ws_size >= need);
  ushort_t* W2t = fused ? (ushort_t*)(w + w2t_off) : W1t;

  // gate (1024) + W1 transpose (4608) overlapped in one launch
  k_gate<<<1024 + 4608, 256, 0, stream>>>(x, Wg, bg, Wm, bm, bv, expert, topp,
                                          score, v, W1, W1t);
  k_thrbucket<<<3, 256, 0, stream>>>(score, thr, expert, meta, tiles, slot_token);
  k_prep<<<MAXSLOTS, 256, 0, stream>>>(x, slot_token, xp);

  if (fused) {
    // gemm1 (960 blocks, scheduled first) + W2 transpose (4608) overlapped;
    // W2t consumed only by gemm2 -> ordering via launch boundary
    k_gemm1<<<NB1 + 4608, 256, 0, stream>>>(xp, W1t, b1, meta, tiles, h, W2,
                                            W2t);
    k_gemm2<<<dim3(MAXTILES, 12, 2), 256, 0, stream>>>(h, W2t, b2, topp, Wv,
                                                       meta, tiles, slot_token,
                                                       outf, v);
  } else {
    // fallback: serial W2 transpose reusing W1t buffer (round-5 sequence)
    k_gemm1<<<NB1, 256, 0, stream>>>(xp, W1t, b1, meta, tiles, h, W2, W2t);
    k_wt<<<4608, 256, 0, stream>>>(W2, W1t, 3072, 768, 48);
    k_gemm2<<<dim3(MAXTILES, 12, 2), 256, 0, stream>>>(h, W1t, b2, topp, Wv,
                                                       meta, tiles, slot_token,
                                                       outf, v);
  }

  k_bkscan<<<4, 256, 0, stream>>>(v, Ar, Ai, Br, Bi);
  k_final<<<NTOK, 256, 0, stream>>>(outf, v, Ar, Ai, Br, Bi, score, thr, Wo, bo, bk);
}

// Round 10
// 323.004 us; speedup vs baseline: 1.1399x; 1.0105x over previous
//
#include <hip/hip_runtime.h>

typedef unsigned short ushort_t;
typedef unsigned int uint32;

#define NTOK 4096
#define SEQ 2048
#define DDIM 768
#define HDIM 3072
#define NEXP 8
#define KKEEP 819
#define MTILE 128
#define MAXTILES 40
#define MAXSLOTS 5120
#define NB1 (MAXTILES * 24)  // gemm1 compute blocks in flattened grid

typedef __attribute__((ext_vector_type(8))) short bfrag8;   // 8 bf16 (4 VGPRs)
typedef __attribute__((ext_vector_type(4))) float facc4;    // 4 fp32 acc

__device__ __forceinline__ ushort_t f2bf(float f) {
  uint32 x = __float_as_uint(f);
  uint32 r = (x + 0x7FFFu + ((x >> 16) & 1u)) >> 16;
  return (ushort_t)r;
}
// gelu = 0.5u(1+tanh(z)) = u / (1 + e^{-2z}), z = 0.79788456(u+0.044715u^3)
// exp2-based: branchless v_exp_f32 + v_rcp_f32 (~8 VALU ops vs ocml tanhf ~60)
__device__ __forceinline__ float gelu_f(float u) {
  float z = u + 0.044715f * u * u * u;
  float e = __builtin_amdgcn_exp2f(-2.3021840216f * z);  // 2*0.79788456*log2(e)
  return u * __builtin_amdgcn_rcpf(1.f + e);
}

// async global->LDS, 16 bytes per lane, LDS dest contiguous in lane order
#define GL2LDS(gp, lp)                                                        \
  __builtin_amdgcn_global_load_lds(                                           \
      (const __attribute__((address_space(1))) void*)(gp),                    \
      (__attribute__((address_space(3))) void*)(lp), 16, 0, 0)

// tile fence: drain this tile's GL2LDS + retired LDS ops, then barrier.
// asm memory clobber = compiler fence; static buffers (As0/As1) let alias
// analysis keep stage(next) and comp(cur) independent (round-4 lesson).
#define TILE_FENCE                                                            \
  asm volatile("s_waitcnt vmcnt(0) lgkmcnt(0)\ns_barrier" ::: "memory")

// shared transpose body: fp32 [e][K][N] 64x64 tile -> bf16 [e][N][K]
__device__ __forceinline__ void wtile_transpose(const float* __restrict__ src,
                                                ushort_t* __restrict__ dst,
                                                int K, int N, int nkb, int bi,
                                                int tid, float (*t)[65]) {
  int per_e = nkb * (N / 64);
  int e = bi / per_e, rem = bi % per_e;
  int k0 = (rem % nkb) * 64, n0 = (rem / nkb) * 64;
  const float* S = src + (size_t)e * K * N;
  ushort_t* D = dst + (size_t)e * N * K;
  int r = tid >> 4, c4 = (tid & 15) * 4;
#pragma unroll
  for (int it = 0; it < 4; ++it) {
    int k = r + it * 16;
    float4 vv = *(const float4*)(S + (size_t)(k0 + k) * N + n0 + c4);
    t[k][c4] = vv.x; t[k][c4 + 1] = vv.y; t[k][c4 + 2] = vv.z; t[k][c4 + 3] = vv.w;
  }
  __syncthreads();
#pragma unroll
  for (int it = 0; it < 4; ++it) {
    int n = r + it * 16;
    ushort4 o;
    o.x = f2bf(t[c4][n]); o.y = f2bf(t[c4 + 1][n]);
    o.z = f2bf(t[c4 + 2][n]); o.w = f2bf(t[c4 + 3][n]);
    *(ushort4*)(D + (size_t)(n0 + n) * K + k0 + c4) = o;
  }
}

// ---------------- gate (bx<1024) + W1 transpose (bx>=1024) ----------------------
__global__ __launch_bounds__(256) void k_gate(
    const float* __restrict__ x, const float* __restrict__ Wg,
    const float* __restrict__ bg, const float* __restrict__ Wm,
    const float* __restrict__ bm, const float* __restrict__ bv,
    int* __restrict__ expert, float* __restrict__ topp,
    float* __restrict__ score, float* __restrict__ v,
    const float* __restrict__ W1, ushort_t* __restrict__ W1t) {
  __shared__ float ts[64][65];
  int tid = threadIdx.x;
  if ((int)blockIdx.x >= 1024) {
    wtile_transpose(W1, W1t, 768, 3072, 12, (int)blockIdx.x - 1024, tid, ts);
    return;
  }
  int lane = tid & 63, w = tid >> 6;
  int t = blockIdx.x * 4 + w;
  float g[8];
#pragma unroll
  for (int e = 0; e < 8; ++e) g[e] = 0.f;
  float sm = 0.f;
  for (int d = lane; d < DDIM; d += 64) {
    float xv = x[(size_t)t * DDIM + d];
    float4 w0 = *(const float4*)(Wg + d * 8);
    float4 w1 = *(const float4*)(Wg + d * 8 + 4);
    g[0] += xv * w0.x; g[1] += xv * w0.y; g[2] += xv * w0.z; g[3] += xv * w0.w;
    g[4] += xv * w1.x; g[5] += xv * w1.y; g[6] += xv * w1.z; g[7] += xv * w1.w;
    sm += xv * Wm[d];
  }
#pragma unroll
  for (int e = 0; e < 8; ++e) {
#pragma unroll
    for (int off = 32; off > 0; off >>= 1) g[e] += __shfl_down(g[e], off, 64);
  }
#pragma unroll
  for (int off = 32; off > 0; off >>= 1) sm += __shfl_down(sm, off, 64);
  if (lane == 0) {
    float l[8];
#pragma unroll
    for (int e = 0; e < 8; ++e) l[e] = g[e] + bg[e];
    int am = 0;
    float mx = l[0];
#pragma unroll
    for (int e = 1; e < 8; ++e) {
      if (l[e] > mx) { mx = l[e]; am = e; }  // first-max = jnp.argmax
    }
    float s = 0.f;
#pragma unroll
    for (int e = 0; e < 8; ++e) s += expf(l[e] - mx);
    expert[t] = am;
    topp[t] = 1.f / s;
    float z = sm + bm[0];
    score[t] = 1.f / (1.f + expf(-z));
    v[t] = bv[0];  // init for gemm2's fused vdot atomic accumulation
  }
}

// ---------------- merged: histogram top-K threshold (b<2) + bucket (b==2) -------
__global__ __launch_bounds__(256) void k_thrbucket(
    const float* __restrict__ score, float* __restrict__ thr,
    const int* __restrict__ expert, int* __restrict__ meta,
    int* __restrict__ tiles, int* __restrict__ slot_token) {
  int tid = threadIdx.x;
  if (blockIdx.x < 2) {
    int b = blockIdx.x;
    __shared__ uint32 chist[256];
    __shared__ float vals[2048];
    __shared__ uint32 scnt;
    __shared__ int bstar_s, kprime_s;
    chist[tid] = 0;
    if (tid == 0) scnt = 0;
    __syncthreads();
    for (int i = tid; i < SEQ; i += 256) {
      float s = score[b * SEQ + i];
      int bin = min(255, max(0, (int)(s * 256.f)));
      atomicAdd(&chist[bin], 1u);
    }
    __syncthreads();
    if (tid == 0) {
      int cum = 0;
      for (int j = 255; j >= 0; --j) {
        cum += (int)chist[j];
        if (cum >= KKEEP) {
          bstar_s = j;
          kprime_s = KKEEP - (cum - (int)chist[j]);
          break;
        }
      }
    }
    __syncthreads();
    int bstar = bstar_s, kprime = kprime_s;
    for (int i = tid; i < SEQ; i += 256) {
      float s = score[b * SEQ + i];
      int bin = min(255, max(0, (int)(s * 256.f)));
      if (bin == bstar) vals[atomicAdd(&scnt, 1u)] = s;
    }
    __syncthreads();
    int n = (int)scnt;
    for (int ci = tid; ci < n; ci += 256) {
      float xx = vals[ci];
      int g = 0, eq = 0;
      for (int j = 0; j < n; ++j) {
        g += (vals[j] > xx);
        eq += (vals[j] == xx);
      }
      if (g < kprime && kprime <= g + eq) thr[b] = xx;  // exact K-th largest
    }
  } else {
    __shared__ int cnt[NEXP];
    __shared__ int off[NEXP];
    if (tid < NEXP) cnt[tid] = 0;
    __syncthreads();
    for (int t = tid; t < NTOK; t += 256) atomicAdd(&cnt[expert[t]], 1);
    __syncthreads();
    if (tid == 0) {
      int run = 0, nt = 0;
      for (int e = 0; e < NEXP; ++e) {
        off[e] = run;
        int c = cnt[e];
        int padded = (c + MTILE - 1) / MTILE * MTILE;
        for (int s = 0; s < padded; s += MTILE)
          tiles[nt++] = (e << 16) | (run + s);
        run += padded;
      }
      meta[0] = nt;
      meta[1] = run;
    }
    __syncthreads();
    for (int s = tid; s < MAXSLOTS; s += 256) slot_token[s] = -1;
    __syncthreads();
    for (int t = tid; t < NTOK; t += 256) {
      int p = atomicAdd(&off[expert[t]], 1);
      slot_token[p] = t;
    }
  }
}

// ---------------- x-gather only (transposes moved to k_gate / k_gemm1) ----------
__global__ __launch_bounds__(256) void k_prep(
    const float* __restrict__ x, const int* __restrict__ slot_token,
    ushort_t* __restrict__ xp) {
  int bx = blockIdx.x;
  int tid = threadIdx.x;
  int tok = slot_token[bx];
  for (int d = tid; d < DDIM; d += 256) {
    float vv = (tok >= 0) ? x[(size_t)tok * DDIM + d] : 0.f;
    xp[(size_t)bx * DDIM + d] = f2bf(vv);
  }
}

// standalone weight transpose (W2) — fallback when workspace too small to fuse
__global__ __launch_bounds__(256) void k_wt(const float* __restrict__ src,
                                            ushort_t* __restrict__ dst, int K,
                                            int N, int nkb) {
  __shared__ float t[64][65];
  wtile_transpose(src, dst, K, N, nkb, blockIdx.x, threadIdx.x, t);
}

// ---------------- gemm1 (bid<NB1) + W2 transpose (bid>=NB1, fused path) ---------
// Round-5 proven gemm config: 128x128 tile, BK=64, coalesced staging, chunk-XOR
// swizzle, 0 conflicts. W2T blocks at grid tail fill idle CU slots and overlap
// the (memory-bound) transpose with the (latency-bound) gemm; W2t is consumed
// only by k_gemm2, ordered by the launch boundary. LDS unioned (32 KB).
__global__ __launch_bounds__(256) void k_gemm1(
    const ushort_t* __restrict__ xp, const ushort_t* __restrict__ Wt,
    const float* __restrict__ b1, const int* __restrict__ meta,
    const int* __restrict__ tiles, ushort_t* __restrict__ h,
    const float* __restrict__ W2, ushort_t* __restrict__ W2t) {
  __shared__ ushort_t smem[16384];  // 32 KB: As|Bs for gemm, t[64][65] for W2T
  int tid = threadIdx.x;
  int bid = blockIdx.x;
  if (bid >= NB1) {
    wtile_transpose(W2, W2t, 3072, 768, 48, bid - NB1,
                    tid, reinterpret_cast<float(*)[65]>(smem));
    return;
  }
  ushort_t* As = smem;          // 128*64
  ushort_t* Bs = smem + 8192;   // 128*64
  int tile = bid % MAXTILES, ny = bid / MAXTILES;  // tile-fast (old 2D order)
  if (tile >= meta[0]) return;
  int desc = tiles[tile];
  int e = desc >> 16, slot0 = desc & 0xFFFF;
  int n0 = ny * 128;
  int lane = tid & 63, w = tid >> 6;
  int mq = (w & 1) << 6, nq = (w >> 1) << 6;
  int mrow = lane & 15, quad = lane >> 4;
  int rl = tid >> 3;                  // row 0..31 (+32 per round)
  int sw = (tid & 7) ^ (rl & 7);      // pre-swizzled global chunk
  const ushort_t* Ag = xp + (size_t)(slot0 + rl) * 768 + sw * 8;
  const ushort_t* Bg = Wt + ((size_t)e * 3072 + n0 + rl) * 768 + sw * 8;
  facc4 acc[4][4];
  facc4 zero = {0.f, 0.f, 0.f, 0.f};
#pragma unroll
  for (int i = 0; i < 4; ++i)
#pragma unroll
    for (int j = 0; j < 4; ++j) acc[i][j] = zero;
  for (int k0 = 0; k0 < 768; k0 += 64) {
#pragma unroll
    for (int r = 0; r < 4; ++r) {
      GL2LDS(Ag + k0 + (size_t)r * 32 * 768, As + (r * 256 + tid) * 8);
      GL2LDS(Bg + k0 + (size_t)r * 32 * 768, Bs + (r * 256 + tid) * 8);
    }
    __syncthreads();
#pragma unroll
    for (int kk = 0; kk < 2; ++kk) {
      bfrag8 a[4], b[4];
      int ph = (((kk << 2) + quad) ^ (mrow & 7)) << 3;
#pragma unroll
      for (int i = 0; i < 4; ++i)
        a[i] = *(const bfrag8*)(As + ((mq + i * 16 + mrow) << 6) + ph);
#pragma unroll
      for (int j = 0; j < 4; ++j)
        b[j] = *(const bfrag8*)(Bs + ((nq + j * 16 + mrow) << 6) + ph);
#pragma unroll
      for (int i = 0; i < 4; ++i)
#pragma unroll
        for (int j = 0; j < 4; ++j)
          acc[i][j] = __builtin_amdgcn_mfma_f32_16x16x32_bf16(a[i], b[j],
                                                              acc[i][j], 0, 0, 0);
    }
    __syncthreads();
  }
  const float* bb = b1 + (size_t)e * 3072 + n0;
#pragma unroll
  for (int i = 0; i < 4; ++i) {
    int mo = mq + i * 16 + (quad << 2);
#pragma unroll
    for (int j = 0; j < 4; ++j) {
      int nc = nq + j * 16 + mrow;
      float bias = bb[nc];
#pragma unroll
      for (int r = 0; r < 4; ++r) {
        float val = gelu_f(acc[i][j][r] + bias);
        h[(size_t)(slot0 + mo + r) * 3072 + n0 + nc] = f2bf(val);
      }
    }
  }
}

// ---------------- grouped MFMA GEMM layer 2 + fused vdot ------------------------
// Round-5 geometry (M-split x2, 64x64 tile, BK=64, [row][64] + 3-bit chunk-XOR,
// 0 conflicts) + STATIC double-buffer 2-phase: four distinct __shared__ arrays
// so alias analysis keeps stage(next) independent of comp(cur) (round-4's
// runtime-indexed buffers forced a conservative vmcnt(0) between them).
// One vmcnt(0)+barrier fence per tile, AFTER compute -> next tile's load
// latency hides under the current tile's ds_read+MFMA phase.
__global__ __launch_bounds__(256) void k_gemm2(
    const ushort_t* __restrict__ h, const ushort_t* __restrict__ Wt,
    const float* __restrict__ b2, const float* __restrict__ topp,
    const float* __restrict__ Wv, const int* __restrict__ meta,
    const int* __restrict__ tiles, const int* __restrict__ slot_token,
    float* __restrict__ outf, float* __restrict__ v) {
  __shared__ ushort_t As0[64 * 64];  // 8 KB each, 32 KB total
  __shared__ ushort_t As1[64 * 64];
  __shared__ ushort_t Bs0[64 * 64];
  __shared__ ushort_t Bs1[64 * 64];
  if ((int)blockIdx.x >= meta[0]) return;
  int desc = tiles[blockIdx.x];
  int e = desc >> 16;
  int slot0 = (desc & 0xFFFF) + ((int)blockIdx.z << 6);  // 64-row half
  int n0 = blockIdx.y * 64;          // 12 n-blocks
  int tid = threadIdx.x;
  int lane = tid & 63, w = tid >> 6;
  int mq = (w & 1) << 5;   // 0 / 32
  int nq = (w >> 1) << 5;  // 0 / 32
  int mrow = lane & 15, quad = lane >> 4;
  int rl = tid >> 3;                  // row 0..31 (+32 per round)
  int sw = (tid & 7) ^ (rl & 7);      // pre-swizzled global chunk
  const ushort_t* Ag = h + (size_t)(slot0 + rl) * 3072 + sw * 8;
  const ushort_t* Bg = Wt + ((size_t)e * 768 + n0 + rl) * 3072 + sw * 8;
  facc4 acc[2][2];
  facc4 zero = {0.f, 0.f, 0.f, 0.f};
#pragma unroll
  for (int i = 0; i < 2; ++i)
#pragma unroll
    for (int j = 0; j < 2; ++j) acc[i][j] = zero;

  auto stage = [&](ushort_t* As, ushort_t* Bs, int k0) {
#pragma unroll
    for (int r = 0; r < 2; ++r) {
      GL2LDS(Ag + k0 + (size_t)r * 32 * 3072, As + (r * 256 + tid) * 8);
      GL2LDS(Bg + k0 + (size_t)r * 32 * 3072, Bs + (r * 256 + tid) * 8);
    }
  };
  auto comp = [&](const ushort_t* As, const ushort_t* Bs) {
#pragma unroll
    for (int kk = 0; kk < 2; ++kk) {
      bfrag8 a[2], b[2];
      int ph = (((kk << 2) + quad) ^ (mrow & 7)) << 3;
#pragma unroll
      for (int i = 0; i < 2; ++i)
        a[i] = *(const bfrag8*)(As + ((mq + i * 16 + mrow) << 6) + ph);
#pragma unroll
      for (int j = 0; j < 2; ++j)
        b[j] = *(const bfrag8*)(Bs + ((nq + j * 16 + mrow) << 6) + ph);
#pragma unroll
      for (int i = 0; i < 2; ++i)
#pragma unroll
        for (int j = 0; j < 2; ++j)
          acc[i][j] = __builtin_amdgcn_mfma_f32_16x16x32_bf16(a[i], b[j],
                                                              acc[i][j], 0, 0, 0);
    }
  };

  stage(As0, Bs0, 0);
  TILE_FENCE;
  // 48 tiles = 24 static pairs; stage(next) issued before comp(cur)
  for (int k0 = 0; k0 < 3072; k0 += 128) {
    stage(As1, Bs1, k0 + 64);
    comp(As0, Bs0);
    TILE_FENCE;
    if (k0 + 128 < 3072) stage(As0, Bs0, k0 + 128);
    comp(As1, Bs1);
    TILE_FENCE;
  }

  const float* bb = b2 + (size_t)e * 768 + n0;
  float wv0 = Wv[n0 + nq + mrow];
  float wv1 = Wv[n0 + nq + 16 + mrow];
  float bb0 = bb[nq + mrow], bb1 = bb[nq + 16 + mrow];
#pragma unroll
  for (int i = 0; i < 2; ++i) {
    int mo = mq + i * 16 + (quad << 2);
#pragma unroll
    for (int r = 0; r < 4; ++r) {
      int slot = slot0 + mo + r;
      int tok = slot_token[slot];  // uniform within 16-lane quad segment
      if (tok < 0) continue;
      float tp = topp[tok];
      float f0 = tp * (acc[i][0][r] + bb0);
      float f1 = tp * (acc[i][1][r] + bb1);
      outf[(size_t)tok * 768 + n0 + nq + mrow] = f0;
      outf[(size_t)tok * 768 + n0 + nq + 16 + mrow] = f1;
      float pv = f0 * wv0 + f1 * wv1;
#pragma unroll
      for (int off = 8; off > 0; off >>= 1) pv += __shfl_down(pv, off, 16);
      if (mrow == 0) atomicAdd(&v[tok], pv);
    }
  }
}

// ---------------- BK parallel scan: Mobius matrices, 3-level scan ---------------
struct CM {
  float ar, ai, br, bi, cr, ci, dr, di;  // [[a,b],[c,d]] complex
};
__device__ __forceinline__ CM cmmul(const CM& A, const CM& B) {  // A*B
  CM C;
  C.ar = A.ar * B.ar - A.ai * B.ai + A.br * B.cr - A.bi * B.ci;
  C.ai = A.ar * B.ai + A.ai * B.ar + A.br * B.ci + A.bi * B.cr;
  C.br = A.ar * B.br - A.ai * B.bi + A.br * B.dr - A.bi * B.di;
  C.bi = A.ar * B.bi + A.ai * B.br + A.br * B.di + A.bi * B.dr;
  C.cr = A.cr * B.ar - A.ci * B.ai + A.dr * B.cr - A.di * B.ci;
  C.ci = A.cr * B.ai + A.ci * B.ar + A.dr * B.ci + A.di * B.cr;
  C.dr = A.cr * B.br - A.ci * B.bi + A.dr * B.dr - A.di * B.di;
  C.di = A.cr * B.bi + A.ci * B.br + A.dr * B.di + A.di * B.dr;
  return C;
}
__device__ __forceinline__ void cmnorm(CM& A) {
  float m = fmaxf(fmaxf(fmaxf(fabsf(A.ar), fabsf(A.ai)),
                        fmaxf(fabsf(A.br), fabsf(A.bi))),
                  fmaxf(fmaxf(fabsf(A.cr), fabsf(A.ci)),
                        fmaxf(fabsf(A.dr), fabsf(A.di))));
  float s = 1.0f / fmaxf(m, 1e-30f);
  A.ar *= s; A.ai *= s; A.br *= s; A.bi *= s;
  A.cr *= s; A.ci *= s; A.dr *= s; A.di *= s;
}
__device__ __forceinline__ CM cmshfl_up(const CM& A, int off) {
  CM B;
  B.ar = __shfl_up(A.ar, off, 64); B.ai = __shfl_up(A.ai, off, 64);
  B.br = __shfl_up(A.br, off, 64); B.bi = __shfl_up(A.bi, off, 64);
  B.cr = __shfl_up(A.cr, off, 64); B.ci = __shfl_up(A.ci, off, 64);
  B.dr = __shfl_up(A.dr, off, 64); B.di = __shfl_up(A.di, off, 64);
  return B;
}

__global__ __launch_bounds__(256) void k_bkscan(
    const float* __restrict__ v, float* __restrict__ Ar, float* __restrict__ Ai,
    float* __restrict__ Br, float* __restrict__ Bi) {
  int b = blockIdx.x >> 1, rev = blockIdx.x & 1;
  int tid = threadIdx.x, lane = tid & 63, wv = tid >> 6;
  const float* vb = v + b * SEQ;
  float dv[8];
  int sbase = tid * 8;
#pragma unroll
  for (int q = 0; q < 8; ++q) {
    int s = sbase + q;
    int n = rev ? (SEQ - 1 - s) : s;
    dv[q] = fminf(3.f, fmaxf(-3.f, vb[n]));
  }
  CM L;
  L.ar = dv[0]; L.ai = -1.f; L.br = -1.f; L.bi = 0.f;
  L.cr = 1.f; L.ci = 0.f; L.dr = 0.f; L.di = 0.f;
#pragma unroll
  for (int q = 1; q < 8; ++q) {
    float dr = dv[q];
    float nar = dr * L.ar + L.ai - L.cr;
    float nai = dr * L.ai - L.ar - L.ci;
    float nbr = dr * L.br + L.bi - L.dr;
    float nbi = dr * L.bi - L.br - L.di;
    L.cr = L.ar; L.ci = L.ai; L.dr = L.br; L.di = L.bi;
    L.ar = nar; L.ai = nai; L.br = nbr; L.bi = nbi;
  }
  cmnorm(L);
  CM I = L;
#pragma unroll
  for (int off = 1; off < 64; off <<= 1) {
    CM P = cmshfl_up(I, off);
    if (lane >= off) {
      I = cmmul(I, P);
      cmnorm(I);
    }
  }
  __shared__ float wag[4][8];
  if (lane == 63) {
    wag[wv][0] = I.ar; wag[wv][1] = I.ai; wag[wv][2] = I.br; wag[wv][3] = I.bi;
    wag[wv][4] = I.cr; wag[wv][5] = I.ci; wag[wv][6] = I.dr; wag[wv][7] = I.di;
  }
  __syncthreads();
  CM E = cmshfl_up(I, 1);
  if (lane == 0) {
    E.ar = 1.f; E.ai = 0.f; E.br = 0.f; E.bi = 0.f;
    E.cr = 0.f; E.ci = 0.f; E.dr = 1.f; E.di = 0.f;
  }
  for (int j = wv - 1; j >= 0; --j) {
    CM Aj;
    Aj.ar = wag[j][0]; Aj.ai = wag[j][1]; Aj.br = wag[j][2]; Aj.bi = wag[j][3];
    Aj.cr = wag[j][4]; Aj.ci = wag[j][5]; Aj.dr = wag[j][6]; Aj.di = wag[j][7];
    E = cmmul(E, Aj);
    cmnorm(E);
  }
  float u0r = E.ar, u0i = E.ai, u1r = E.cr, u1i = E.ci;
  float* Rr = rev ? Br : Ar;
  float* Ri = rev ? Bi : Ai;
#pragma unroll
  for (int q = 0; q < 8; ++q) {
    float dr = dv[q];
    float n0r = dr * u0r + u0i - u1r;
    float n0i = dr * u0i - u0r - u1i;
    u1r = u0r; u1i = u0i; u0r = n0r; u0i = n0i;
    float m = fmaxf(fmaxf(fabsf(u0r), fabsf(u0i)), fmaxf(fabsf(u1r), fabsf(u1i)));
    float sc = 1.f / fmaxf(m, 1e-30f);
    u0r *= sc; u0i *= sc; u1r *= sc; u1i *= sc;
    float den = u1r * u1r + u1i * u1i;
    float arr = (u0r * u1r + u0i * u1i) / den;
    float aii = (u0i * u1r - u0r * u1i) / den;
    int s = sbase + q;
    int n = rev ? (SEQ - 1 - s) : s;
    Rr[b * SEQ + n] = arr;
    Ri[b * SEQ + n] = aii;
  }
}

// ---------------- final (in place on d_out): out += bk_scale*(feats@Wo+bo) ------
__global__ __launch_bounds__(256) void k_final(
    float* __restrict__ outf, const float* __restrict__ v,
    const float* __restrict__ Ar, const float* __restrict__ Ai,
    const float* __restrict__ Br, const float* __restrict__ Bi,
    const float* __restrict__ score, const float* __restrict__ thr,
    const float* __restrict__ Wo, const float* __restrict__ bo,
    const float* __restrict__ bk) {
  int t = blockIdx.x;
  int b = t >> 11;
  float vc = fminf(3.f, fmaxf(-3.f, v[t]));
  float cr = Ar[t] + Br[t] - vc;
  float ci = Ai[t] + Bi[t] + 1.f;
  float den = cr * cr + ci * ci;
  float gr = cr / den, gi = -ci / den;
  bool m = (score[t] >= thr[b]);
  float fr = m ? fminf(10.f, fmaxf(-10.f, gr)) : 0.f;
  float fi = m ? fminf(10.f, fmaxf(-10.f, gi)) : 0.f;
  float bs = bk[0];
  for (int d = threadIdx.x; d < DDIM; d += 256) {
    float o = outf[(size_t)t * DDIM + d] +
              bs * (fr * Wo[d] + fi * Wo[DDIM + d] + bo[d]);
    outf[(size_t)t * DDIM + d] = o;
  }
}

extern "C" void kernel_launch(void* const* d_in, const int* in_sizes, int n_in,
                              void* d_out, int out_size, void* d_ws, size_t ws_size,
                              hipStream_t stream) {
  const float* x  = (const float*)d_in[0];
  const float* Wg = (const float*)d_in[1];
  const float* bg = (const float*)d_in[2];
  const float* W1 = (const float*)d_in[3];
  const float* b1 = (const float*)d_in[4];
  const float* W2 = (const float*)d_in[5];
  const float* b2 = (const float*)d_in[6];
  const float* Wv = (const float*)d_in[7];
  const float* bv = (const float*)d_in[8];
  const float* Wm = (const float*)d_in[9];
  const float* bm = (const float*)d_in[10];
  const float* Wo = (const float*)d_in[11];
  const float* bo = (const float*)d_in[12];
  const float* bk = (const float*)d_in[13];
  float* outf = (float*)d_out;

  unsigned char* w = (unsigned char*)d_ws;
  int*   expert     = (int*)(w + 0);
  float* topp       = (float*)(w + 16384);
  float* score      = (float*)(w + 32768);
  float* v          = (float*)(w + 49152);
  float* Ar         = (float*)(w + 65536);
  float* Ai         = (float*)(w + 81920);
  float* Br         = (float*)(w + 98304);
  float* Bi         = (float*)(w + 114688);
  float* thr        = (float*)(w + 131072);
  int*   meta       = (int*)(w + 131104);
  int*   tiles      = (int*)(w + 131136);
  int*   slot_token = (int*)(w + 131328);            // 5120 ints
  ushort_t* xp      = (ushort_t*)(w + 152064);       // 5120*768  bf16 = 7.9 MB
  ushort_t* h       = (ushort_t*)(w + 8016384);      // 5120*3072 bf16 = 31.5 MB
  ushort_t* W1t     = (ushort_t*)(w + 39473664);     // 8*3072*768 bf16 = 37.7 MB
  // optional separate W2t right after W1t (fused path): +37.7 MB -> ~115 MB total
  size_t w2t_off = 39473664ull + 37748736ull;        // 77222400
  size_t need    = w2t_off + 37748736ull;            // 114971136
  bool fused = (ws_size >= need);
  ushort_t* W2t = fused ? (ushort_t*)(w + w2t_off) : W1t;

  // gate (1024) + W1 transpose (4608) overlapped in one launch
  k_gate<<<1024 + 4608, 256, 0, stream>>>(x, Wg, bg, Wm, bm, bv, expert, topp,
                                          score, v, W1, W1t);
  k_thrbucket<<<3, 256, 0, stream>>>(score, thr, expert, meta, tiles, slot_token);
  k_prep<<<MAXSLOTS, 256, 0, stream>>>(x, slot_token, xp);

  if (fused) {
    // gemm1 (960 blocks, scheduled first) + W2 transpose (4608) overlapped;
    // W2t consumed only by gemm2 -> ordering via launch boundary
    k_gemm1<<<NB1 + 4608, 256, 0, stream>>>(xp, W1t, b1, meta, tiles, h, W2,
                                            W2t);
    k_gemm2<<<dim3(MAXTILES, 12, 2), 256, 0, stream>>>(h, W2t, b2, topp, Wv,
                                                       meta, tiles, slot_token,
                                                       outf, v);
  } else {
    // fallback: serial W2 transpose reusing W1t buffer (round-5 sequence)
    k_gemm1<<<NB1, 256, 0, stream>>>(xp, W1t, b1, meta, tiles, h, W2, W2t);
    k_wt<<<4608, 256, 0, stream>>>(W2, W1t, 3072, 768, 48);
    k_gemm2<<<dim3(MAXTILES, 12, 2), 256, 0, stream>>>(h, W1t, b2, topp, Wv,
                                                       meta, tiles, slot_token,
                                                       outf, v);
  }

  k_bkscan<<<4, 256, 0, stream>>>(v, Ar, Ai, Br, Bi);
  k_final<<<NTOK, 256, 0, stream>>>(outf, v, Ar, Ai, Br, Bi, score, thr, Wo, bo, bk);
}